// Round 1
// baseline (296.562 us; speedup 1.0000x reference)
//
#include <hip/hip_runtime.h>
#include <hip/hip_bf16.h>

typedef __attribute__((ext_vector_type(8))) short short8;
typedef __attribute__((ext_vector_type(4))) float float4v;
typedef __attribute__((ext_vector_type(16))) float float16v;
typedef _Float16 half4v __attribute__((ext_vector_type(4)));

#define NB 32
#define LL 128
#define DDIM 300
#define DP 320
#define KDIM 50
#define WP 328   // wtile pitch (bf16 elems)
#define TP 40    // Tt/e2t pitch
#define SLAB_OFF 18759680ull
#define SLAB_BYTES (50ull * 32ull * 16384ull * 2ull)          // 52,428,800
#define WS_NEED  (SLAB_OFF + SLAB_BYTES)

__device__ __forceinline__ unsigned short f2bf(float x) {
    unsigned int u = __float_as_uint(x);
    unsigned int r = (u + 0x7FFFu + ((u >> 16) & 1u)) >> 16;
    return (unsigned short)r;
}
__device__ __forceinline__ unsigned int pack2bf(float a, float b) {
    return (unsigned int)f2bf(a) | ((unsigned int)f2bf(b) << 16);
}
__device__ __forceinline__ float4v mfma16(short8 a, short8 b, float4v c) {
    return __builtin_amdgcn_mfma_f32_16x16x32_bf16(a, b, c, 0, 0, 0);
}
__device__ __forceinline__ float16v mfma32(short8 a, short8 b, float16v c) {
    return __builtin_amdgcn_mfma_f32_32x32x16_bf16(a, b, c, 0, 0, 0);
}

// ---------- fused prep: [0,500) Wb->Wbt arm; [500,1012) projections+convert arm ----------
__global__ void prep_all(const float* __restrict__ e1, const float* __restrict__ e2,
                         const float* __restrict__ Wb,
                         const float* __restrict__ Wd, const float* __restrict__ Wg,
                         unsigned short* __restrict__ e1b, unsigned short* __restrict__ e2b,
                         unsigned short* __restrict__ wbt,
                         float* __restrict__ p1d, float* __restrict__ p1g,
                         float* __restrict__ p2d, float* __restrict__ p2g) {
    const int blk = blockIdx.x;
    __shared__ float tile[32][33];

    if (blk < 500) {
        // ---- Wb transpose arm: (k, e-tile), dt loop inside ----
        int k = blk / 10, et = blk % 10;
        int tx = threadIdx.x & 31, ty = threadIdx.x >> 5;
        for (int dt = 0; dt < 10; ++dt) {
#pragma unroll
            for (int rr = 0; rr < 4; ++rr) {
                int d = dt * 32 + ty + rr * 8;
                int e = et * 32 + tx;
                tile[ty + rr * 8][tx] = (d < DDIM && e < DDIM) ? Wb[((size_t)k * DDIM + d) * DDIM + e] : 0.f;
            }
            __syncthreads();
#pragma unroll
            for (int rr = 0; rr < 4; ++rr) {
                int e = et * 32 + ty + rr * 8;
                int d = dt * 32 + tx;
                wbt[((size_t)k * DP + e) * DP + d] = f2bf(tile[tx][ty + rr * 8]);
            }
            __syncthreads();
        }
        return;
    }
    // ---- projection + conversion arm: 512 blocks, 16 rows each ----
    int bid = blk - 500;
    const int kk = threadIdx.x & 63;
    const int grp = threadIdx.x >> 6;
    const int kks = kk < KDIM ? kk : 0;
    const float* src; int woff; float *dd, *dg; int r0;
    unsigned short* bdst;
    int rowbase = bid * 16;
    if (rowbase < 4096) { r0 = rowbase; src = e1; woff = 0; dd = p1d; dg = p1g; bdst = e1b; }
    else { r0 = rowbase - 4096; src = e2; woff = DDIM; dd = p2d; dg = p2g; bdst = e2b; }
    const float* e0 = src + (size_t)(r0 + grp * 4) * DDIM;
    const float* wdp = Wd + (size_t)woff * KDIM + kks;
    const float* wgp = Wg + (size_t)woff * KDIM + kks;

    float ad[4] = {0.f, 0.f, 0.f, 0.f}, ag[4] = {0.f, 0.f, 0.f, 0.f};
    for (int c = 0; c < DDIM / 4; ++c) {
        const int d0 = c * 4;
        float4 x[4];
#pragma unroll
        for (int rr = 0; rr < 4; ++rr)
            x[rr] = *(const float4*)(e0 + (size_t)rr * DDIM + d0);
        float wd0 = wdp[(size_t)(d0 + 0) * KDIM];
        float wd1 = wdp[(size_t)(d0 + 1) * KDIM];
        float wd2 = wdp[(size_t)(d0 + 2) * KDIM];
        float wd3 = wdp[(size_t)(d0 + 3) * KDIM];
        float wg0 = wgp[(size_t)(d0 + 0) * KDIM];
        float wg1 = wgp[(size_t)(d0 + 1) * KDIM];
        float wg2 = wgp[(size_t)(d0 + 2) * KDIM];
        float wg3 = wgp[(size_t)(d0 + 3) * KDIM];
#pragma unroll
        for (int rr = 0; rr < 4; ++rr) {
            ad[rr] += x[rr].x * wd0 + x[rr].y * wd1 + x[rr].z * wd2 + x[rr].w * wd3;
            ag[rr] += x[rr].x * wg0 + x[rr].y * wg1 + x[rr].z * wg2 + x[rr].w * wg3;
        }
    }
    if (kk < KDIM) {
#pragma unroll
        for (int rr = 0; rr < 4; ++rr) {
            size_t o = (size_t)(r0 + grp * 4 + rr) * KDIM + kk;
            dd[o] = ad[rr];
            dg[o] = ag[rr];
        }
    }
    // conversion: this block's 16 rows -> bf16 padded (640 granules of 8)
    for (int it = 0; it < 3; ++it) {
        int g = threadIdx.x + it * 256;
        if (g >= 640) break;
        int rl = g / 40, d0 = (g % 40) * 8;
        const float* sp = src + (size_t)(r0 + rl) * DDIM;
        unsigned short* dp = bdst + (size_t)(r0 + rl) * DP + d0;
        float v[8];
        if (d0 + 8 <= DDIM) {
            float4 lo = *(const float4*)(sp + d0);
            float4 hi = *(const float4*)(sp + d0 + 4);
            v[0] = lo.x; v[1] = lo.y; v[2] = lo.z; v[3] = lo.w;
            v[4] = hi.x; v[5] = hi.y; v[6] = hi.z; v[7] = hi.w;
        } else if (d0 < DDIM) {          // d0 == 296
            float4 lo = *(const float4*)(sp + d0);
            v[0] = lo.x; v[1] = lo.y; v[2] = lo.z; v[3] = lo.w;
            v[4] = v[5] = v[6] = v[7] = 0.f;
        } else {
            for (int j = 0; j < 8; ++j) v[j] = 0.f;
        }
        unsigned short tmp[8];
#pragma unroll
        for (int j = 0; j < 8; ++j) tmp[j] = f2bf(v[j]);
        *(short8*)dp = *(short8*)tmp;
    }
}

// ---------- main: per (b,k): S = (e1 Wb[k]) e2^T, gate ----------
// R8 dataflow + R9: occupancy 2->3 blocks/CU (LDS 43.5KB x3 fits 160KB),
// and early-issue of phase-2 e2t B-fragments (reg prefetch right after the
// barrier) so their LDS latency hides under the phase-1 MFMA chain.
template <int SLAB>
__global__ __launch_bounds__(256, 3) void grn_main(
    const unsigned short* __restrict__ e1b, const unsigned short* __restrict__ e2b,
    const unsigned short* __restrict__ wbt,
    const float* __restrict__ p1d, const float* __restrict__ p1g,
    const float* __restrict__ p2d, const float* __restrict__ p2g,
    const float* __restrict__ bg, const float* __restrict__ bb,
    const float* __restrict__ u, float* __restrict__ out, _Float16* __restrict__ slab) {
    const int b = blockIdx.x, k = blockIdx.y;
    const int tid = threadIdx.x;
    const int wid = tid >> 6, lane = tid & 63;
    const int q = lane >> 4, ln = lane & 15;
    const int l32 = lane & 31, hi = lane >> 5;     // 32x32 fragment coords
    const int rw0 = wid * 32;                      // wave owns i-rows [rw0, rw0+32)

    __shared__ __align__(16) unsigned short wtile[32 * WP];   // Wbt tile [e'][d]
    __shared__ __align__(16) unsigned short Tt[128 * TP];     // T tile   [i][e']
    __shared__ __align__(16) unsigned short e2t[128 * TP];    // e2 tile  [j][e']
    __shared__ float pbuf[4][128];

    if (tid < 128) {
        int gi = (b * LL + tid) * KDIM + k;
        pbuf[0][tid] = p1d[gi];
        pbuf[1][tid] = p1g[gi];
        pbuf[2][tid] = p2d[gi];
        pbuf[3][tid] = p2g[gi];
    }
    const float u_k = u[k], bg_k = bg[k], b_k = bb[k];

    const unsigned short* wbt_k = wbt + (size_t)k * DP * DP;
    size_t wgo[5]; int wlo[5];
#pragma unroll
    for (int it = 0; it < 5; ++it) {
        int c = tid + it * 256, r = c / 40, col = (c % 40) * 8;
        wgo[it] = (size_t)r * DP + col;
        wlo[it] = r * WP + col;
    }
    size_t ego[2]; int elo[2];
#pragma unroll
    for (int it = 0; it < 2; ++it) {
        int c = tid + it * 256, j = c >> 2, col = (c & 3) * 8;
        ego[it] = (size_t)(b * LL + j) * DP + col;
        elo[it] = j * TP + col;
    }

    // e1 B-fragments for 32x32x16: lane holds e1[i=rw0+l32][d=c*16+hi*8+j], c=0..19
    short8 af[20];
    {
        const unsigned short* p = e1b + ((size_t)(b * LL + rw0 + l32)) * DP + hi * 8;
#pragma unroll
        for (int c = 0; c < 20; ++c)
            af[c] = *(const short8*)(p + c * 16);
    }

    float4v S[2][8];
#pragma unroll
    for (int mt = 0; mt < 2; ++mt)
#pragma unroll
        for (int nt = 0; nt < 8; ++nt)
            S[mt][nt] = (float4v){0.f, 0.f, 0.f, 0.f};

    // prefetch tile 0
    short8 wpre[5], epre[2];
#pragma unroll
    for (int it = 0; it < 5; ++it) wpre[it] = *(const short8*)(wbt_k + wgo[it]);
#pragma unroll
    for (int it = 0; it < 2; ++it) epre[it] = *(const short8*)(e2b + ego[it]);

    char* twr = (char*)Tt + (rw0 + ln) * 80;        // phase-2 read base (ln 0..15)
    char* tww = (char*)Tt + (rw0 + l32) * 80;       // phase-1 write base (l32 0..31)

    for (int et = 0; et < 10; ++et) {
#pragma unroll
        for (int it = 0; it < 5; ++it) *(short8*)&wtile[wlo[it]] = wpre[it];
#pragma unroll
        for (int it = 0; it < 2; ++it) *(short8*)&e2t[elo[it]] = epre[it];
        __syncthreads();

        // early-issue phase-2 B fragments: latency hides under phase-1 MFMA chain
        short8 bfr[8];
#pragma unroll
        for (int nt = 0; nt < 8; ++nt)
            bfr[nt] = *(const short8*)&e2t[(nt * 16 + ln) * TP + q * 8];

        if (et < 9) {
            const size_t ew = (size_t)(et + 1) * 32 * DP;
            const int ee = (et + 1) * 32;
#pragma unroll
            for (int it = 0; it < 5; ++it) wpre[it] = *(const short8*)(wbt_k + ew + wgo[it]);
#pragma unroll
            for (int it = 0; it < 2; ++it) epre[it] = *(const short8*)(e2b + ego[it] + ee);
        }

        // phase 1 (32x32x16): C[m=e'][n=i] = sum_d Wb[e'][d]*e1[i][d]
        // A = wtile: lane reads row e'=l32, d = c*16 + hi*8 (16B). 2 chains.
        float16v t0, t1;
#pragma unroll
        for (int z = 0; z < 16; ++z) { t0[z] = 0.f; t1[z] = 0.f; }
#pragma unroll
        for (int c = 0; c < 20; c += 2) {
            short8 wa0 = *(const short8*)&wtile[l32 * WP + c * 16 + hi * 8];
            short8 wa1 = *(const short8*)&wtile[l32 * WP + (c + 1) * 16 + hi * 8];
            t0 = mfma32(wa0, af[c], t0);
            t1 = mfma32(wa1, af[c + 1], t1);
        }
        float16v tt = t0 + t1;
        // C layout: i = l32, e' = (r&3) + 8*(r>>2) + 4*hi  ->  Tt[i][e']
        // group g=r>>2: 4 consecutive e' at g*8+hi*4 -> one b64 each
#pragma unroll
        for (int g = 0; g < 4; ++g) {
            uint2 v;
            v.x = pack2bf(tt[g * 4 + 0], tt[g * 4 + 1]);
            v.y = pack2bf(tt[g * 4 + 2], tt[g * 4 + 3]);
            *(uint2*)(tww + g * 16 + hi * 8) = v;
        }
        // phase 2 (16x16x32): S[i][j] += sum_e' T[i][e'] * e2t[j][e']
        short8 a0 = *(const short8*)(twr + q * 16);
        short8 a1 = *(const short8*)(twr + 16 * 80 + q * 16);
#pragma unroll
        for (int nt = 0; nt < 8; ++nt) {
            S[0][nt] = mfma16(a0, bfr[nt], S[0][nt]);
            S[1][nt] = mfma16(a1, bfr[nt], S[1][nt]);
        }
        __syncthreads();
    }

    // epilogue: gate, mix, scale by u[k]
    float pdi[2][4], pgi[2][4];
#pragma unroll
    for (int mt = 0; mt < 2; ++mt)
#pragma unroll
        for (int r = 0; r < 4; ++r) {
            int i = rw0 + mt * 16 + q * 4 + r;
            pdi[mt][r] = pbuf[0][i];
            pgi[mt][r] = pbuf[1][i];
        }
    _Float16* sdst = slab + ((size_t)k * NB + b) * 16384;
    float* adst = out + (size_t)b * LL * LL;
#pragma unroll
    for (int nt = 0; nt < 8; ++nt) {
        int j = nt * 16 + ln;
        float pdj = pbuf[2][j];
        float pgj = pbuf[3][j] + bg_k;
#pragma unroll
        for (int mt = 0; mt < 2; ++mt)
#pragma unroll
            for (int r = 0; r < 4; ++r) {
                int i = rw0 + mt * 16 + q * 4 + r;
                float btp = S[mt][nt][r];
                float sd = pdi[mt][r] + pdj;
                float sg = pgi[mt][r] + pgj;
                float e2x = __expf(2.f * sd);
                float sln = 1.f - 2.f * __builtin_amdgcn_rcpf(e2x + 1.f);   // tanh(sd)
                float g = __builtin_amdgcn_rcpf(1.f + __expf(-sg));          // sigmoid(sg)
                float val = u_k * (g * btp + (1.f - g) * sln + b_k);
                if (SLAB) {
                    // permuted coalesced layout: pos = v*256 + tid, v = nt*8+mt*4+r
                    sdst[(nt * 8 + mt * 4 + r) * 256 + tid] = (_Float16)val;
                } else {
                    unsafeAtomicAdd(adst + (size_t)i * LL + j, val);
                }
            }
    }
}

// ---------- reduce: out[b][i][j] = sum_k slab[k][b][pos]; decode permutation ----------
__global__ void reduce_k(const _Float16* __restrict__ slab, float* __restrict__ out) {
    int idx = blockIdx.x * 256 + threadIdx.x;     // 0..131071
    int b = idx >> 12;
    int p4 = idx & 4095;
    int pos0 = p4 * 4;
    int v = pos0 >> 8, tid0 = pos0 & 255;
    int nt = v >> 3, mt = (v >> 2) & 1, r = v & 3;
    int wid = tid0 >> 6, q = (tid0 >> 4) & 3, ln0 = tid0 & 15;
    int i = wid * 32 + mt * 16 + q * 4 + r;
    int j0 = nt * 16 + ln0;

    float a0 = 0.f, a1 = 0.f, a2 = 0.f, a3 = 0.f;
    const _Float16* sp = slab + (size_t)b * 16384 + pos0;
#pragma unroll
    for (int k = 0; k < KDIM; ++k) {
        half4v h = *(const half4v*)(sp + (size_t)k * (NB * 16384));
        a0 += (float)h[0]; a1 += (float)h[1]; a2 += (float)h[2]; a3 += (float)h[3];
    }
    float4 rv; rv.x = a0; rv.y = a1; rv.z = a2; rv.w = a3;
    *(float4*)(out + (size_t)b * 16384 + i * 128 + j0) = rv;
}

extern "C" void kernel_launch(void* const* d_in, const int* in_sizes, int n_in,
                              void* d_out, int out_size, void* d_ws, size_t ws_size,
                              hipStream_t stream) {
    const float* e1 = (const float*)d_in[0];   // (32,128,300)
    const float* e2 = (const float*)d_in[1];   // (32,128,300)
    const float* Wb = (const float*)d_in[2];   // (50,300,300)
    const float* Wd = (const float*)d_in[3];   // (600,50)
    const float* Wg = (const float*)d_in[4];   // (600,50)
    const float* bg = (const float*)d_in[5];   // (50,)
    const float* bb = (const float*)d_in[6];   // (50,)
    const float* u  = (const float*)d_in[7];   // (50,1)
    float* out = (float*)d_out;                // (32,128,128,1)

    unsigned short* e1b = (unsigned short*)d_ws;                 // 1,310,720 elems
    unsigned short* e2b = e1b + 1310720;                         // 1,310,720 elems
    unsigned short* wbt = e2b + 1310720;                         // 5,120,000 elems
    float* pf  = (float*)((char*)d_ws + 15482880);
    float* p1d = pf;
    float* p1g = pf + 204800;
    float* p2d = pf + 409600;
    float* p2g = pf + 614400;                                    // end 18,759,680 B
    _Float16* slab = (_Float16*)((char*)d_ws + SLAB_OFF);        // 50x32x16384 halves

    prep_all<<<1012, 256, 0, stream>>>(e1, e2, Wb, Wd, Wg,
                                       e1b, e2b, wbt,
                                       p1d, p1g, p2d, p2g);

    if (ws_size >= WS_NEED) {
        grn_main<1><<<dim3(NB, KDIM), 256, 0, stream>>>(e1b, e2b, wbt,
                                                        p1d, p1g, p2d, p2g,
                                                        bg, bb, u, out, slab);
        reduce_k<<<512, 256, 0, stream>>>(slab, out);
    } else {
        hipMemsetAsync(d_out, 0, (size_t)out_size * sizeof(float), stream);
        grn_main<0><<<dim3(NB, KDIM), 256, 0, stream>>>(e1b, e2b, wbt,
                                                        p1d, p1g, p2d, p2g,
                                                        bg, bb, u, out, slab);
    }
}

// Round 2
// 266.386 us; speedup vs baseline: 1.1133x; 1.1133x over previous
//
#include <hip/hip_runtime.h>
#include <hip/hip_bf16.h>

typedef __attribute__((ext_vector_type(8))) short short8;
typedef __attribute__((ext_vector_type(4))) float float4v;
typedef __attribute__((ext_vector_type(16))) float float16v;
typedef _Float16 half4v __attribute__((ext_vector_type(4)));

#define NB 32
#define LL 128
#define DDIM 300
#define DP 320
#define KDIM 50
#define WP 328   // wtile pitch (bf16 elems)
#define TP 40    // Tt pitch
#define SLAB_OFF 18759680ull
#define SLAB_BYTES (50ull * 32ull * 16384ull * 2ull)          // 52,428,800
#define WS_NEED  (SLAB_OFF + SLAB_BYTES)

__device__ __forceinline__ unsigned short f2bf(float x) {
    unsigned int u = __float_as_uint(x);
    unsigned int r = (u + 0x7FFFu + ((u >> 16) & 1u)) >> 16;
    return (unsigned short)r;
}
__device__ __forceinline__ unsigned int pack2bf(float a, float b) {
    return (unsigned int)f2bf(a) | ((unsigned int)f2bf(b) << 16);
}
__device__ __forceinline__ float4v mfma16(short8 a, short8 b, float4v c) {
    return __builtin_amdgcn_mfma_f32_16x16x32_bf16(a, b, c, 0, 0, 0);
}
__device__ __forceinline__ float16v mfma32(short8 a, short8 b, float16v c) {
    return __builtin_amdgcn_mfma_f32_32x32x16_bf16(a, b, c, 0, 0, 0);
}

// ---------- fused prep: [0,500) Wb->Wbt arm; [500,1012) projections+convert arm ----------
__global__ void prep_all(const float* __restrict__ e1, const float* __restrict__ e2,
                         const float* __restrict__ Wb,
                         const float* __restrict__ Wd, const float* __restrict__ Wg,
                         unsigned short* __restrict__ e1b, unsigned short* __restrict__ e2b,
                         unsigned short* __restrict__ wbt,
                         float* __restrict__ p1d, float* __restrict__ p1g,
                         float* __restrict__ p2d, float* __restrict__ p2g) {
    const int blk = blockIdx.x;
    __shared__ float tile[32][33];

    if (blk < 500) {
        // ---- Wb transpose arm: (k, e-tile), dt loop inside ----
        int k = blk / 10, et = blk % 10;
        int tx = threadIdx.x & 31, ty = threadIdx.x >> 5;
        for (int dt = 0; dt < 10; ++dt) {
#pragma unroll
            for (int rr = 0; rr < 4; ++rr) {
                int d = dt * 32 + ty + rr * 8;
                int e = et * 32 + tx;
                tile[ty + rr * 8][tx] = (d < DDIM && e < DDIM) ? Wb[((size_t)k * DDIM + d) * DDIM + e] : 0.f;
            }
            __syncthreads();
#pragma unroll
            for (int rr = 0; rr < 4; ++rr) {
                int e = et * 32 + ty + rr * 8;
                int d = dt * 32 + tx;
                wbt[((size_t)k * DP + e) * DP + d] = f2bf(tile[tx][ty + rr * 8]);
            }
            __syncthreads();
        }
        return;
    }
    // ---- projection + conversion arm: 512 blocks, 16 rows each ----
    int bid = blk - 500;
    const int kk = threadIdx.x & 63;
    const int grp = threadIdx.x >> 6;
    const int kks = kk < KDIM ? kk : 0;
    const float* src; int woff; float *dd, *dg; int r0;
    unsigned short* bdst;
    int rowbase = bid * 16;
    if (rowbase < 4096) { r0 = rowbase; src = e1; woff = 0; dd = p1d; dg = p1g; bdst = e1b; }
    else { r0 = rowbase - 4096; src = e2; woff = DDIM; dd = p2d; dg = p2g; bdst = e2b; }
    const float* e0 = src + (size_t)(r0 + grp * 4) * DDIM;
    const float* wdp = Wd + (size_t)woff * KDIM + kks;
    const float* wgp = Wg + (size_t)woff * KDIM + kks;

    float ad[4] = {0.f, 0.f, 0.f, 0.f}, ag[4] = {0.f, 0.f, 0.f, 0.f};
    for (int c = 0; c < DDIM / 4; ++c) {
        const int d0 = c * 4;
        float4 x[4];
#pragma unroll
        for (int rr = 0; rr < 4; ++rr)
            x[rr] = *(const float4*)(e0 + (size_t)rr * DDIM + d0);
        float wd0 = wdp[(size_t)(d0 + 0) * KDIM];
        float wd1 = wdp[(size_t)(d0 + 1) * KDIM];
        float wd2 = wdp[(size_t)(d0 + 2) * KDIM];
        float wd3 = wdp[(size_t)(d0 + 3) * KDIM];
        float wg0 = wgp[(size_t)(d0 + 0) * KDIM];
        float wg1 = wgp[(size_t)(d0 + 1) * KDIM];
        float wg2 = wgp[(size_t)(d0 + 2) * KDIM];
        float wg3 = wgp[(size_t)(d0 + 3) * KDIM];
#pragma unroll
        for (int rr = 0; rr < 4; ++rr) {
            ad[rr] += x[rr].x * wd0 + x[rr].y * wd1 + x[rr].z * wd2 + x[rr].w * wd3;
            ag[rr] += x[rr].x * wg0 + x[rr].y * wg1 + x[rr].z * wg2 + x[rr].w * wg3;
        }
    }
    if (kk < KDIM) {
#pragma unroll
        for (int rr = 0; rr < 4; ++rr) {
            size_t o = (size_t)(r0 + grp * 4 + rr) * KDIM + kk;
            dd[o] = ad[rr];
            dg[o] = ag[rr];
        }
    }
    // conversion: this block's 16 rows -> bf16 padded (640 granules of 8)
    for (int it = 0; it < 3; ++it) {
        int g = threadIdx.x + it * 256;
        if (g >= 640) break;
        int rl = g / 40, d0 = (g % 40) * 8;
        const float* sp = src + (size_t)(r0 + rl) * DDIM;
        unsigned short* dp = bdst + (size_t)(r0 + rl) * DP + d0;
        float v[8];
        if (d0 + 8 <= DDIM) {
            float4 lo = *(const float4*)(sp + d0);
            float4 hi = *(const float4*)(sp + d0 + 4);
            v[0] = lo.x; v[1] = lo.y; v[2] = lo.z; v[3] = lo.w;
            v[4] = hi.x; v[5] = hi.y; v[6] = hi.z; v[7] = hi.w;
        } else if (d0 < DDIM) {          // d0 == 296
            float4 lo = *(const float4*)(sp + d0);
            v[0] = lo.x; v[1] = lo.y; v[2] = lo.z; v[3] = lo.w;
            v[4] = v[5] = v[6] = v[7] = 0.f;
        } else {
            for (int j = 0; j < 8; ++j) v[j] = 0.f;
        }
        unsigned short tmp[8];
#pragma unroll
        for (int j = 0; j < 8; ++j) tmp[j] = f2bf(v[j]);
        *(short8*)dp = *(short8*)tmp;
    }
}

// ---------- main: per (b,k): S = (e1 Wb[k]) e2^T, gate ----------
// R10: software-pipelined. Body n = phase2(n-1) || phase1(n), branch-free.
//  - wtile double-buffered (one barrier per iteration, classic dbuf)
//  - Tt double-buffered (wave-private: write->read gap spans a whole iter, no
//    extra barrier needed; roundtrip latency off the critical path)
//  - e2 B-fragments read directly from global (L2-resident, 16 rows x 64B
//    coalesced per instr) -> e2t LDS buffer + its stage traffic removed
//  - __launch_bounds__(256,2): R1 showed the unified VGPR+AGPR file caps this
//    kernel at 2 blocks/CU; forcing 3 spills af[20] (FETCH 52->339MB).
template <int SLAB>
__global__ __launch_bounds__(256, 2) void grn_main(
    const unsigned short* __restrict__ e1b, const unsigned short* __restrict__ e2b,
    const unsigned short* __restrict__ wbt,
    const float* __restrict__ p1d, const float* __restrict__ p1g,
    const float* __restrict__ p2d, const float* __restrict__ p2g,
    const float* __restrict__ bg, const float* __restrict__ bb,
    const float* __restrict__ u, float* __restrict__ out, _Float16* __restrict__ slab) {
    const int b = blockIdx.x, k = blockIdx.y;
    const int tid = threadIdx.x;
    const int wid = tid >> 6, lane = tid & 63;
    const int q = lane >> 4, ln = lane & 15;
    const int l32 = lane & 31, hi = lane >> 5;     // 32x32 fragment coords
    const int rw0 = wid * 32;                      // wave owns i-rows [rw0, rw0+32)

    __shared__ __align__(16) unsigned short wtile[2][32 * WP];  // Wbt tile [e'][d], dbuf
    __shared__ __align__(16) unsigned short Tt[2][128 * TP];    // T tile [i][e'], dbuf
    __shared__ float pbuf[4][128];

    if (tid < 128) {
        int gi = (b * LL + tid) * KDIM + k;
        pbuf[0][tid] = p1d[gi];
        pbuf[1][tid] = p1g[gi];
        pbuf[2][tid] = p2d[gi];
        pbuf[3][tid] = p2g[gi];
    }
    const float u_k = u[k], bg_k = bg[k], b_k = bb[k];

    const unsigned short* wbt_k = wbt + (size_t)k * DP * DP;
    int wgo[5], wlo[5];
#pragma unroll
    for (int it = 0; it < 5; ++it) {
        int c = tid + it * 256, r = c / 40, col = (c % 40) * 8;
        wgo[it] = r * DP + col;
        wlo[it] = r * WP + col;
    }
    // per-lane base for direct-global e2 B-fragments:
    // frag(nt, et) = e2b[(b*LL + nt*16 + ln)*DP + et*32 + q*8], 16B
    const unsigned short* e2p = e2b + (size_t)(b * LL + ln) * DP + q * 8;

    // e1 B-fragments for 32x32x16: lane holds e1[i=rw0+l32][d=c*16+hi*8+j], c=0..19
    short8 af[20];
    {
        const unsigned short* p = e1b + ((size_t)(b * LL + rw0 + l32)) * DP + hi * 8;
#pragma unroll
        for (int c = 0; c < 20; ++c)
            af[c] = *(const short8*)(p + c * 16);
    }

    float4v S[2][8];
#pragma unroll
    for (int mt = 0; mt < 2; ++mt)
#pragma unroll
        for (int nt = 0; nt < 8; ++nt)
            S[mt][nt] = (float4v){0.f, 0.f, 0.f, 0.f};

    // prefetch tile 0 (wtile stage regs + e2 fragments et=0)
    short8 wpre[5], bfr[8];
#pragma unroll
    for (int it = 0; it < 5; ++it) wpre[it] = *(const short8*)(wbt_k + wgo[it]);
#pragma unroll
    for (int nt = 0; nt < 8; ++nt) bfr[nt] = *(const short8*)(e2p + nt * 16 * DP);

    const int TTB = 128 * TP * 2;                   // bytes per Tt buffer
    char* tww = (char*)&Tt[0][0] + (rw0 + l32) * 80;  // phase-1 write base (l32 0..31)
    char* twr = (char*)&Tt[0][0] + (rw0 + ln) * 80;   // phase-2 read base  (ln 0..15)

#pragma unroll
    for (int it = 0; it < 5; ++it) *(short8*)&wtile[0][wlo[it]] = wpre[it];
    __syncthreads();

    // ---- peeled iter 0: phase1 only ----
#pragma unroll
    for (int it = 0; it < 5; ++it) wpre[it] = *(const short8*)(wbt_k + 32 * DP + wgo[it]);
    {
        float16v t0, t1;
#pragma unroll
        for (int z = 0; z < 16; ++z) { t0[z] = 0.f; t1[z] = 0.f; }
#pragma unroll
        for (int c = 0; c < 20; c += 2) {
            short8 wa0 = *(const short8*)&wtile[0][l32 * WP + c * 16 + hi * 8];
            short8 wa1 = *(const short8*)&wtile[0][l32 * WP + (c + 1) * 16 + hi * 8];
            t0 = mfma32(wa0, af[c], t0);
            t1 = mfma32(wa1, af[c + 1], t1);
        }
        float16v tt = t0 + t1;
#pragma unroll
        for (int g = 0; g < 4; ++g) {
            uint2 v;
            v.x = pack2bf(tt[g * 4 + 0], tt[g * 4 + 1]);
            v.y = pack2bf(tt[g * 4 + 2], tt[g * 4 + 3]);
            *(uint2*)(tww + g * 16 + hi * 8) = v;
        }
    }
#pragma unroll
    for (int it = 0; it < 5; ++it) *(short8*)&wtile[1][wlo[it]] = wpre[it];
    __syncthreads();

    // ---- steady loop: body n = phase2(n-1) || phase1(n) ----
    for (int n = 1; n < 10; ++n) {
        const int pc = n & 1, pp = pc ^ 1;
        // phase2(n-1): S += T(n-1) * e2(n-1)^T   (Tt[pp], bfr holds et=n-1)
        {
            char* tr = twr + pp * TTB;
            short8 a0 = *(const short8*)(tr + q * 16);
            short8 a1 = *(const short8*)(tr + 16 * 80 + q * 16);
#pragma unroll
            for (int nt = 0; nt < 8; ++nt) {
                S[0][nt] = mfma16(a0, bfr[nt], S[0][nt]);
                S[1][nt] = mfma16(a1, bfr[nt], S[1][nt]);
            }
        }
        // refill e2 fragments (et = n) and wtile stage regs (et = n+1, clamped)
        {
            const unsigned short* ep = e2p + n * 32;
#pragma unroll
            for (int nt = 0; nt < 8; ++nt) bfr[nt] = *(const short8*)(ep + nt * 16 * DP);
        }
        {
            const int nn = n < 9 ? n + 1 : 9;      // clamp: last prefetch is dead
            const unsigned short* wp = wbt_k + nn * 32 * DP;
#pragma unroll
            for (int it = 0; it < 5; ++it) wpre[it] = *(const short8*)(wp + wgo[it]);
        }
        // phase1(n): T(n) = Wb-tile(n) * e1   (reads wtile[pc], writes Tt[pc])
        {
            const unsigned short* wt = &wtile[pc][0];
            float16v t0, t1;
#pragma unroll
            for (int z = 0; z < 16; ++z) { t0[z] = 0.f; t1[z] = 0.f; }
#pragma unroll
            for (int c = 0; c < 20; c += 2) {
                short8 wa0 = *(const short8*)&wt[l32 * WP + c * 16 + hi * 8];
                short8 wa1 = *(const short8*)&wt[l32 * WP + (c + 1) * 16 + hi * 8];
                t0 = mfma32(wa0, af[c], t0);
                t1 = mfma32(wa1, af[c + 1], t1);
            }
            float16v tt = t0 + t1;
            char* tw = tww + pc * TTB;
#pragma unroll
            for (int g = 0; g < 4; ++g) {
                uint2 v;
                v.x = pack2bf(tt[g * 4 + 0], tt[g * 4 + 1]);
                v.y = pack2bf(tt[g * 4 + 2], tt[g * 4 + 3]);
                *(uint2*)(tw + g * 16 + hi * 8) = v;
            }
        }
        // stage wtile for iter n+1 (dead for n=9, harmless)
#pragma unroll
        for (int it = 0; it < 5; ++it) *(short8*)&wtile[pp][wlo[it]] = wpre[it];
        __syncthreads();
    }

    // epilogue phase2(9): Tt parity = 9&1 = 1, bfr holds et=9
    {
        char* tr = twr + 1 * TTB;
        short8 a0 = *(const short8*)(tr + q * 16);
        short8 a1 = *(const short8*)(tr + 16 * 80 + q * 16);
#pragma unroll
        for (int nt = 0; nt < 8; ++nt) {
            S[0][nt] = mfma16(a0, bfr[nt], S[0][nt]);
            S[1][nt] = mfma16(a1, bfr[nt], S[1][nt]);
        }
    }

    // epilogue: gate, mix, scale by u[k]
    float pdi[2][4], pgi[2][4];
#pragma unroll
    for (int mt = 0; mt < 2; ++mt)
#pragma unroll
        for (int r = 0; r < 4; ++r) {
            int i = rw0 + mt * 16 + q * 4 + r;
            pdi[mt][r] = pbuf[0][i];
            pgi[mt][r] = pbuf[1][i];
        }
    _Float16* sdst = slab + ((size_t)k * NB + b) * 16384;
    float* adst = out + (size_t)b * LL * LL;
#pragma unroll
    for (int nt = 0; nt < 8; ++nt) {
        int j = nt * 16 + ln;
        float pdj = pbuf[2][j];
        float pgj = pbuf[3][j] + bg_k;
#pragma unroll
        for (int mt = 0; mt < 2; ++mt)
#pragma unroll
            for (int r = 0; r < 4; ++r) {
                int i = rw0 + mt * 16 + q * 4 + r;
                float btp = S[mt][nt][r];
                float sd = pdi[mt][r] + pdj;
                float sg = pgi[mt][r] + pgj;
                float e2x = __expf(2.f * sd);
                float sln = 1.f - 2.f * __builtin_amdgcn_rcpf(e2x + 1.f);   // tanh(sd)
                float g = __builtin_amdgcn_rcpf(1.f + __expf(-sg));          // sigmoid(sg)
                float val = u_k * (g * btp + (1.f - g) * sln + b_k);
                if (SLAB) {
                    // permuted coalesced layout: pos = v*256 + tid, v = nt*8+mt*4+r
                    sdst[(nt * 8 + mt * 4 + r) * 256 + tid] = (_Float16)val;
                } else {
                    unsafeAtomicAdd(adst + (size_t)i * LL + j, val);
                }
            }
    }
}

// ---------- reduce: out[b][i][j] = sum_k slab[k][b][pos]; decode permutation ----------
__global__ void reduce_k(const _Float16* __restrict__ slab, float* __restrict__ out) {
    int idx = blockIdx.x * 256 + threadIdx.x;     // 0..131071
    int b = idx >> 12;
    int p4 = idx & 4095;
    int pos0 = p4 * 4;
    int v = pos0 >> 8, tid0 = pos0 & 255;
    int nt = v >> 3, mt = (v >> 2) & 1, r = v & 3;
    int wid = tid0 >> 6, q = (tid0 >> 4) & 3, ln0 = tid0 & 15;
    int i = wid * 32 + mt * 16 + q * 4 + r;
    int j0 = nt * 16 + ln0;

    float a0 = 0.f, a1 = 0.f, a2 = 0.f, a3 = 0.f;
    const _Float16* sp = slab + (size_t)b * 16384 + pos0;
#pragma unroll
    for (int k = 0; k < KDIM; ++k) {
        half4v h = *(const half4v*)(sp + (size_t)k * (NB * 16384));
        a0 += (float)h[0]; a1 += (float)h[1]; a2 += (float)h[2]; a3 += (float)h[3];
    }
    float4 rv; rv.x = a0; rv.y = a1; rv.z = a2; rv.w = a3;
    *(float4*)(out + (size_t)b * 16384 + i * 128 + j0) = rv;
}

extern "C" void kernel_launch(void* const* d_in, const int* in_sizes, int n_in,
                              void* d_out, int out_size, void* d_ws, size_t ws_size,
                              hipStream_t stream) {
    const float* e1 = (const float*)d_in[0];   // (32,128,300)
    const float* e2 = (const float*)d_in[1];   // (32,128,300)
    const float* Wb = (const float*)d_in[2];   // (50,300,300)
    const float* Wd = (const float*)d_in[3];   // (600,50)
    const float* Wg = (const float*)d_in[4];   // (600,50)
    const float* bg = (const float*)d_in[5];   // (50,)
    const float* bb = (const float*)d_in[6];   // (50,)
    const float* u  = (const float*)d_in[7];   // (50,1)
    float* out = (float*)d_out;                // (32,128,128,1)

    unsigned short* e1b = (unsigned short*)d_ws;                 // 1,310,720 elems
    unsigned short* e2b = e1b + 1310720;                         // 1,310,720 elems
    unsigned short* wbt = e2b + 1310720;                         // 5,120,000 elems
    float* pf  = (float*)((char*)d_ws + 15482880);
    float* p1d = pf;
    float* p1g = pf + 204800;
    float* p2d = pf + 409600;
    float* p2g = pf + 614400;                                    // end 18,759,680 B
    _Float16* slab = (_Float16*)((char*)d_ws + SLAB_OFF);        // 50x32x16384 halves

    prep_all<<<1012, 256, 0, stream>>>(e1, e2, Wb, Wd, Wg,
                                       e1b, e2b, wbt,
                                       p1d, p1g, p2d, p2g);

    if (ws_size >= WS_NEED) {
        grn_main<1><<<dim3(NB, KDIM), 256, 0, stream>>>(e1b, e2b, wbt,
                                                        p1d, p1g, p2d, p2g,
                                                        bg, bb, u, out, slab);
        reduce_k<<<512, 256, 0, stream>>>(slab, out);
    } else {
        hipMemsetAsync(d_out, 0, (size_t)out_size * sizeof(float), stream);
        grn_main<0><<<dim3(NB, KDIM), 256, 0, stream>>>(e1b, e2b, wbt,
                                                        p1d, p1g, p2d, p2g,
                                                        bg, bb, u, out, slab);
    }
}

// Round 3
// 235.373 us; speedup vs baseline: 1.2600x; 1.1318x over previous
//
#include <hip/hip_runtime.h>
#include <hip/hip_bf16.h>

typedef __attribute__((ext_vector_type(8))) short short8;
typedef __attribute__((ext_vector_type(16))) float float16v;
typedef __attribute__((ext_vector_type(4))) int int4v;
typedef __attribute__((ext_vector_type(2))) int int2v;
typedef _Float16 half4v __attribute__((ext_vector_type(4)));

#define NB 32
#define LL 128
#define DDIM 300
#define DP 320
#define KDIM 50
#define WTILE_E 10240            // elems per (k, et) wtile: 32 rows x 320
#define WBT_K   102400           // elems per k (10 tiles)
#define SLAB_OFF 18759680ull
#define SLAB_BYTES (50ull * 32ull * 16384ull * 2ull)          // 52,428,800
#define WS_NEED  (SLAB_OFF + SLAB_BYTES)

__device__ __forceinline__ unsigned short f2bf(float x) {
    unsigned int u = __float_as_uint(x);
    unsigned int r = (u + 0x7FFFu + ((u >> 16) & 1u)) >> 16;
    return (unsigned short)r;
}
__device__ __forceinline__ float16v mfma32(short8 a, short8 b, float16v c) {
    return __builtin_amdgcn_mfma_f32_32x32x16_bf16(a, b, c, 0, 0, 0);
}
__device__ __forceinline__ unsigned int cvtpk(float lo, float hi) {
    unsigned int r;
    asm("v_cvt_pk_bf16_f32 %0, %1, %2" : "=v"(r) : "v"(lo), "v"(hi));
    return r;
}
__device__ __forceinline__ void gload_lds16(const void* g, void* l) {
    __builtin_amdgcn_global_load_lds((const __attribute__((address_space(1))) void*)g,
                                     (__attribute__((address_space(3))) void*)l, 16, 0, 0);
}

// ---------- fused prep: [0,500) Wb->Wbt arm; [500,1012) projections+convert arm ----------
// Wbt layout (R3): per (k, et) a LINEAR 20480B tile, XOR swizzle pre-applied:
//   elem offset = k*102400 + et*10240 + (e&31)*320 + (d ^ ((e&7)<<3))
// so grn_main can stage it with global_load_lds (linear dest) and read with
// the same XOR (4-way bank conflict, equal to the old +8 pad).
__global__ void prep_all(const float* __restrict__ e1, const float* __restrict__ e2,
                         const float* __restrict__ Wb,
                         const float* __restrict__ Wd, const float* __restrict__ Wg,
                         unsigned short* __restrict__ e1b, unsigned short* __restrict__ e2b,
                         unsigned short* __restrict__ wbt,
                         float* __restrict__ p1d, float* __restrict__ p1g,
                         float* __restrict__ p2d, float* __restrict__ p2g) {
    const int blk = blockIdx.x;
    __shared__ float tile[32][33];

    if (blk < 500) {
        // ---- Wb transpose arm: (k, e-tile), dt loop inside ----
        int k = blk / 10, et = blk % 10;
        int tx = threadIdx.x & 31, ty = threadIdx.x >> 5;
        for (int dt = 0; dt < 10; ++dt) {
#pragma unroll
            for (int rr = 0; rr < 4; ++rr) {
                int d = dt * 32 + ty + rr * 8;
                int e = et * 32 + tx;
                tile[ty + rr * 8][tx] = (d < DDIM && e < DDIM) ? Wb[((size_t)k * DDIM + d) * DDIM + e] : 0.f;
            }
            __syncthreads();
#pragma unroll
            for (int rr = 0; rr < 4; ++rr) {
                int e = et * 32 + ty + rr * 8;     // global e'
                int d = dt * 32 + tx;
                size_t off = (size_t)k * WBT_K + (size_t)et * WTILE_E
                           + (size_t)(e & 31) * 320 + (size_t)(d ^ ((e & 7) << 3));
                wbt[off] = f2bf(tile[tx][ty + rr * 8]);
            }
            __syncthreads();
        }
        return;
    }
    // ---- projection + conversion arm: 512 blocks, 16 rows each ----
    int bid = blk - 500;
    const int kk = threadIdx.x & 63;
    const int grp = threadIdx.x >> 6;
    const int kks = kk < KDIM ? kk : 0;
    const float* src; int woff; float *dd, *dg; int r0;
    unsigned short* bdst;
    int rowbase = bid * 16;
    if (rowbase < 4096) { r0 = rowbase; src = e1; woff = 0; dd = p1d; dg = p1g; bdst = e1b; }
    else { r0 = rowbase - 4096; src = e2; woff = DDIM; dd = p2d; dg = p2g; bdst = e2b; }
    const float* e0 = src + (size_t)(r0 + grp * 4) * DDIM;
    const float* wdp = Wd + (size_t)woff * KDIM + kks;
    const float* wgp = Wg + (size_t)woff * KDIM + kks;

    float ad[4] = {0.f, 0.f, 0.f, 0.f}, ag[4] = {0.f, 0.f, 0.f, 0.f};
    for (int c = 0; c < DDIM / 4; ++c) {
        const int d0 = c * 4;
        float4 x[4];
#pragma unroll
        for (int rr = 0; rr < 4; ++rr)
            x[rr] = *(const float4*)(e0 + (size_t)rr * DDIM + d0);
        float wd0 = wdp[(size_t)(d0 + 0) * KDIM];
        float wd1 = wdp[(size_t)(d0 + 1) * KDIM];
        float wd2 = wdp[(size_t)(d0 + 2) * KDIM];
        float wd3 = wdp[(size_t)(d0 + 3) * KDIM];
        float wg0 = wgp[(size_t)(d0 + 0) * KDIM];
        float wg1 = wgp[(size_t)(d0 + 1) * KDIM];
        float wg2 = wgp[(size_t)(d0 + 2) * KDIM];
        float wg3 = wgp[(size_t)(d0 + 3) * KDIM];
#pragma unroll
        for (int rr = 0; rr < 4; ++rr) {
            ad[rr] += x[rr].x * wd0 + x[rr].y * wd1 + x[rr].z * wd2 + x[rr].w * wd3;
            ag[rr] += x[rr].x * wg0 + x[rr].y * wg1 + x[rr].z * wg2 + x[rr].w * wg3;
        }
    }
    if (kk < KDIM) {
#pragma unroll
        for (int rr = 0; rr < 4; ++rr) {
            size_t o = (size_t)(r0 + grp * 4 + rr) * KDIM + kk;
            dd[o] = ad[rr];
            dg[o] = ag[rr];
        }
    }
    // conversion: this block's 16 rows -> bf16 padded (640 granules of 8)
    for (int it = 0; it < 3; ++it) {
        int g = threadIdx.x + it * 256;
        if (g >= 640) break;
        int rl = g / 40, d0 = (g % 40) * 8;
        const float* sp = src + (size_t)(r0 + rl) * DDIM;
        unsigned short* dp = bdst + (size_t)(r0 + rl) * DP + d0;
        float v[8];
        if (d0 + 8 <= DDIM) {
            float4 lo = *(const float4*)(sp + d0);
            float4 hi = *(const float4*)(sp + d0 + 4);
            v[0] = lo.x; v[1] = lo.y; v[2] = lo.z; v[3] = lo.w;
            v[4] = hi.x; v[5] = hi.y; v[6] = hi.z; v[7] = hi.w;
        } else if (d0 < DDIM) {          // d0 == 296
            float4 lo = *(const float4*)(sp + d0);
            v[0] = lo.x; v[1] = lo.y; v[2] = lo.z; v[3] = lo.w;
            v[4] = v[5] = v[6] = v[7] = 0.f;
        } else {
            for (int j = 0; j < 8; ++j) v[j] = 0.f;
        }
        unsigned short tmp[8];
#pragma unroll
        for (int j = 0; j < 8; ++j) tmp[j] = f2bf(v[j]);
        *(short8*)dp = *(short8*)tmp;
    }
}

// ---------- main: per (b,k): S = (e1 Wb[k]) e2^T, gate ----------
// R3: in-register T hand-off.
//  phase1 (mfma32): T[e'][i] for this wave's 32 i-rows; C-layout gives lane
//    (l32,hi) the 32 e' values of column i=l32 in tt[16]x(hi half).
//  cvt_pk + permlane32_swap rearrange tt into phase-2 A-fragments
//    A[i=l32][e'=ks*16+hi*8+j] entirely in registers (no Tt LDS roundtrip).
//  phase2 (mfma32): S[i][j] += T*e2^T, B-frags straight from global e2b (L2).
//  wtile: global_load_lds staging (zero staging VGPRs), dbuf, 1 barrier/iter;
//    source pre-swizzled in prep, reads XOR the same swizzle (4-way banks).
//  Register budget (R1/R2 lesson: 256/wave hard cap at 2 blocks/CU):
//    af 80 + S 64 + t0/t1 32 + bfr 16 + misc ~ 215.
template <int SLAB>
__global__ __launch_bounds__(256, 2) void grn_main(
    const unsigned short* __restrict__ e1b, const unsigned short* __restrict__ e2b,
    const unsigned short* __restrict__ wbt,
    const float* __restrict__ p1d, const float* __restrict__ p1g,
    const float* __restrict__ p2d, const float* __restrict__ p2g,
    const float* __restrict__ bg, const float* __restrict__ bb,
    const float* __restrict__ u, float* __restrict__ out, _Float16* __restrict__ slab) {
    const int b = blockIdx.x, k = blockIdx.y;
    const int tid = threadIdx.x;
    const int wid = tid >> 6, lane = tid & 63;
    const int l32 = lane & 31, hi = lane >> 5;
    const int rw0 = wid * 32;                      // wave owns i-rows [rw0, rw0+32)

    __shared__ __align__(16) unsigned short wtile[2][WTILE_E];  // 2 x 20480B, linear+swz
    __shared__ float pbuf[4][128];

    const unsigned short* wsrc = wbt + (size_t)k * WBT_K;

    // prologue: stage tile 0 (each wave: 5 chunks of 1024B, linear dest)
#pragma unroll
    for (int it = 0; it < 5; ++it) {
        int c = wid * 5 + it;
        gload_lds16(wsrc + c * 512 + lane * 8, &wtile[0][c * 512]);
    }

    if (tid < 128) {
        int gi = (b * LL + tid) * KDIM + k;
        pbuf[0][tid] = p1d[gi];
        pbuf[1][tid] = p1g[gi];
        pbuf[2][tid] = p2d[gi];
        pbuf[3][tid] = p2g[gi];
    }
    const float u_k = u[k], bg_k = bg[k], b_k = bb[k];

    // e1 B-fragments (phase1): lane holds e1[i=rw0+l32][d=c*16+hi*8+j], c=0..19
    short8 af[20];
    {
        const unsigned short* p = e1b + ((size_t)(b * LL + rw0 + l32)) * DP + hi * 8;
#pragma unroll
        for (int c = 0; c < 20; ++c)
            af[c] = *(const short8*)(p + c * 16);
    }

    // e2 B-fragment base (phase2): lane (l32,hi) reads
    //   e2[j=jt*32+l32][e' = et*32 + ks*16 + hi*8 + jj]
    const unsigned short* e2base = e2b + (size_t)(b * LL + l32) * DP + hi * 8;

    float16v S[4];
#pragma unroll
    for (int jt = 0; jt < 4; ++jt)
#pragma unroll
        for (int z = 0; z < 16; ++z) S[jt][z] = 0.f;

    const int swz = (l32 & 7) << 3;                 // phase1 read swizzle (elems)

    __syncthreads();                                 // tile0 + pbuf ready

    for (int et = 0; et < 10; ++et) {
        const int cur = et & 1;
        // ks0 B-frags for this et (cover = phase1)
        short8 b0[4];
        {
            const unsigned short* ep = e2base + et * 32;
#pragma unroll
            for (int jt = 0; jt < 4; ++jt)
                b0[jt] = *(const short8*)(ep + jt * 32 * DP);
        }
        // stage next tile (dbuf; drained by next barrier's vmcnt(0))
        if (et < 9) {
            const unsigned short* ws = wsrc + (et + 1) * WTILE_E;
            unsigned short* ld = &wtile[cur ^ 1][0];
#pragma unroll
            for (int it = 0; it < 5; ++it) {
                int c = wid * 5 + it;
                gload_lds16(ws + c * 512 + lane * 8, ld + c * 512);
            }
        }

        // phase 1 (mfma32): C[m=e'][n=i] = sum_d Wb[e'][d]*e1[i][d]
        const unsigned short* wt = &wtile[cur][l32 * 320];
        float16v t0, t1;
#pragma unroll
        for (int z = 0; z < 16; ++z) { t0[z] = 0.f; t1[z] = 0.f; }
#pragma unroll
        for (int c = 0; c < 20; c += 2) {
            short8 wa0 = *(const short8*)(wt + ((c * 16 + hi * 8) ^ swz));
            short8 wa1 = *(const short8*)(wt + (((c + 1) * 16 + hi * 8) ^ swz));
            t0 = mfma32(wa0, af[c], t0);
            t1 = mfma32(wa1, af[c + 1], t1);
        }
        // ks1 B-frags (cover = pack/swap + ks0 MFMAs)
        short8 b1[4];
        {
            const unsigned short* ep = e2base + et * 32 + 16;
#pragma unroll
            for (int jt = 0; jt < 4; ++jt)
                b1[jt] = *(const short8*)(ep + jt * 32 * DP);
        }
        float16v tt = t0 + t1;
        // pack to bf16 pairs; lane (l32,hi) holds T[i=l32][e'=(r&3)+8*(r>>2)+4*hi]
        unsigned int P0 = cvtpk(tt[0], tt[1]);
        unsigned int P1 = cvtpk(tt[2], tt[3]);
        unsigned int P2 = cvtpk(tt[4], tt[5]);
        unsigned int P3 = cvtpk(tt[6], tt[7]);
        unsigned int P4 = cvtpk(tt[8], tt[9]);
        unsigned int P5 = cvtpk(tt[10], tt[11]);
        unsigned int P6 = cvtpk(tt[12], tt[13]);
        unsigned int P7 = cvtpk(tt[14], tt[15]);
        // half-wave exchange: dst'={dst_lo,src_lo}, src'={dst_hi,src_hi}
        int2v r02 = __builtin_amdgcn_permlane32_swap((int)P0, (int)P2, false, false);
        int2v r13 = __builtin_amdgcn_permlane32_swap((int)P1, (int)P3, false, false);
        int2v r46 = __builtin_amdgcn_permlane32_swap((int)P4, (int)P6, false, false);
        int2v r57 = __builtin_amdgcn_permlane32_swap((int)P5, (int)P7, false, false);
        short8 A0 = __builtin_bit_cast(short8, (int4v){r02[0], r13[0], r02[1], r13[1]});
        short8 A1 = __builtin_bit_cast(short8, (int4v){r46[0], r57[0], r46[1], r57[1]});
        // phase 2 (mfma32): S[i][j] += sum_e' T[i][e'] * e2[j][e']
#pragma unroll
        for (int jt = 0; jt < 4; ++jt)
            S[jt] = mfma32(A0, b0[jt], S[jt]);
#pragma unroll
        for (int jt = 0; jt < 4; ++jt)
            S[jt] = mfma32(A1, b1[jt], S[jt]);

        __syncthreads();   // publishes next tile (vmcnt drain) / guards dbuf reuse
    }

    // epilogue: gate, mix, scale by u[k]
    // S[jt][r]: i = rw0 + (r&3)+8*(r>>2)+4*hi, j = jt*32 + l32
    float pdj[4], pgj[4];
#pragma unroll
    for (int jt = 0; jt < 4; ++jt) {
        pdj[jt] = pbuf[2][jt * 32 + l32];
        pgj[jt] = pbuf[3][jt * 32 + l32] + bg_k;
    }
    _Float16* sdst = slab + ((size_t)k * NB + b) * 16384;
    float* adst = out + (size_t)b * LL * LL;
#pragma unroll
    for (int r = 0; r < 16; ++r) {
        int i = rw0 + (r & 3) + 8 * (r >> 2) + 4 * hi;
        float pdi_ = pbuf[0][i];
        float pgi_ = pbuf[1][i];
#pragma unroll
        for (int jt = 0; jt < 4; ++jt) {
            float btp = S[jt][r];
            float sd = pdi_ + pdj[jt];
            float sg = pgi_ + pgj[jt];
            float e2x = __expf(2.f * sd);
            float sln = 1.f - 2.f * __builtin_amdgcn_rcpf(e2x + 1.f);   // tanh(sd)
            float g = __builtin_amdgcn_rcpf(1.f + __expf(-sg));          // sigmoid(sg)
            float val = u_k * (g * btp + (1.f - g) * sln + b_k);
            if (SLAB) {
                // permuted coalesced layout: pos = v*256 + tid, v = jt*16 + r
                sdst[(jt * 16 + r) * 256 + tid] = (_Float16)val;
            } else {
                unsafeAtomicAdd(adst + (size_t)i * LL + (jt * 32 + l32), val);
            }
        }
    }
}

// ---------- reduce: out[b][i][j] = sum_k slab[k][b][pos]; decode permutation ----------
__global__ void reduce_k(const _Float16* __restrict__ slab, float* __restrict__ out) {
    int idx = blockIdx.x * 256 + threadIdx.x;     // 0..131071
    int b = idx >> 12;
    int p4 = idx & 4095;
    int pos0 = p4 * 4;
    int v = pos0 >> 8, tid0 = pos0 & 255;
    int jt = v >> 4, r = v & 15;
    int wid = tid0 >> 6, lane = tid0 & 63, hi2 = lane >> 5, l32 = lane & 31;
    int i = wid * 32 + (r & 3) + 8 * (r >> 2) + 4 * hi2;
    int j0 = jt * 32 + l32;

    float a0 = 0.f, a1 = 0.f, a2 = 0.f, a3 = 0.f;
    const _Float16* sp = slab + (size_t)b * 16384 + pos0;
#pragma unroll
    for (int k = 0; k < KDIM; ++k) {
        half4v h = *(const half4v*)(sp + (size_t)k * (NB * 16384));
        a0 += (float)h[0]; a1 += (float)h[1]; a2 += (float)h[2]; a3 += (float)h[3];
    }
    float4 rv; rv.x = a0; rv.y = a1; rv.z = a2; rv.w = a3;
    *(float4*)(out + (size_t)b * 16384 + i * 128 + j0) = rv;
}

extern "C" void kernel_launch(void* const* d_in, const int* in_sizes, int n_in,
                              void* d_out, int out_size, void* d_ws, size_t ws_size,
                              hipStream_t stream) {
    const float* e1 = (const float*)d_in[0];   // (32,128,300)
    const float* e2 = (const float*)d_in[1];   // (32,128,300)
    const float* Wb = (const float*)d_in[2];   // (50,300,300)
    const float* Wd = (const float*)d_in[3];   // (600,50)
    const float* Wg = (const float*)d_in[4];   // (600,50)
    const float* bg = (const float*)d_in[5];   // (50,)
    const float* bb = (const float*)d_in[6];   // (50,)
    const float* u  = (const float*)d_in[7];   // (50,1)
    float* out = (float*)d_out;                // (32,128,128,1)

    unsigned short* e1b = (unsigned short*)d_ws;                 // 1,310,720 elems
    unsigned short* e2b = e1b + 1310720;                         // 1,310,720 elems
    unsigned short* wbt = e2b + 1310720;                         // 5,120,000 elems
    float* pf  = (float*)((char*)d_ws + 15482880);
    float* p1d = pf;
    float* p1g = pf + 204800;
    float* p2d = pf + 409600;
    float* p2g = pf + 614400;                                    // end 18,759,680 B
    _Float16* slab = (_Float16*)((char*)d_ws + SLAB_OFF);        // 50x32x16384 halves

    prep_all<<<1012, 256, 0, stream>>>(e1, e2, Wb, Wd, Wg,
                                       e1b, e2b, wbt,
                                       p1d, p1g, p2d, p2g);

    if (ws_size >= WS_NEED) {
        grn_main<1><<<dim3(NB, KDIM), 256, 0, stream>>>(e1b, e2b, wbt,
                                                        p1d, p1g, p2d, p2g,
                                                        bg, bb, u, out, slab);
        reduce_k<<<512, 256, 0, stream>>>(slab, out);
    } else {
        hipMemsetAsync(d_out, 0, (size_t)out_size * sizeof(float), stream);
        grn_main<0><<<dim3(NB, KDIM), 256, 0, stream>>>(e1b, e2b, wbt,
                                                        p1d, p1g, p2d, p2g,
                                                        bg, bb, u, out, slab);
    }
}

// Round 4
// 230.872 us; speedup vs baseline: 1.2845x; 1.0195x over previous
//
#include <hip/hip_runtime.h>
#include <hip/hip_bf16.h>

typedef __attribute__((ext_vector_type(8))) short short8;
typedef __attribute__((ext_vector_type(16))) float float16v;
typedef __attribute__((ext_vector_type(4))) int int4v;
typedef __attribute__((ext_vector_type(2))) int int2v;
typedef _Float16 half4v __attribute__((ext_vector_type(4)));

#define NB 32
#define LL 128
#define DDIM 300
#define DP 320
#define KDIM 50
#define WTILE_E 10240            // elems per (k, et) wtile: 32 rows x 320
#define WBT_K   102400           // elems per k (10 tiles)
#define E2TILE_E 4096            // elems per (b, et) e2 tile: 4 granules x 128 j x 8
#define SLAB_OFF 18759680ull
#define SLAB_BYTES (50ull * 32ull * 16384ull * 2ull)          // 52,428,800
#define WS_NEED  (SLAB_OFF + SLAB_BYTES)

__device__ __forceinline__ unsigned short f2bf(float x) {
    unsigned int u = __float_as_uint(x);
    unsigned int r = (u + 0x7FFFu + ((u >> 16) & 1u)) >> 16;
    return (unsigned short)r;
}
__device__ __forceinline__ float16v mfma32(short8 a, short8 b, float16v c) {
    return __builtin_amdgcn_mfma_f32_32x32x16_bf16(a, b, c, 0, 0, 0);
}
__device__ __forceinline__ unsigned int cvtpk(float lo, float hi) {
    unsigned int r;
    asm("v_cvt_pk_bf16_f32 %0, %1, %2" : "=v"(r) : "v"(lo), "v"(hi));
    return r;
}
__device__ __forceinline__ void gload_lds16(const void* g, void* l) {
    __builtin_amdgcn_global_load_lds((const __attribute__((address_space(1))) void*)g,
                                     (__attribute__((address_space(3))) void*)l, 16, 0, 0);
}

// ---------- fused prep: [0,500) Wb->Wbt arm; [500,1012) projections+convert arm ----------
// Wbt layout (R3): per (k, et) a LINEAR 20480B tile, XOR swizzle pre-applied:
//   elem offset = k*102400 + et*10240 + (e&31)*320 + (d ^ ((e&7)<<3))
// e2til layout (R4): per (b, et) a LINEAR 8192B tile, granule-major:
//   elem offset = ((b*10 + et)*4 + g)*1024 + j*8 + jj     (g = e'granule 0..3)
// Both are staged with global_load_lds (linear dest); e2til phase-2 reads are
// conflict-free (lane stride 16B).
__global__ void prep_all(const float* __restrict__ e1, const float* __restrict__ e2,
                         const float* __restrict__ Wb,
                         const float* __restrict__ Wd, const float* __restrict__ Wg,
                         unsigned short* __restrict__ e1b, unsigned short* __restrict__ e2til,
                         unsigned short* __restrict__ wbt,
                         float* __restrict__ p1d, float* __restrict__ p1g,
                         float* __restrict__ p2d, float* __restrict__ p2g) {
    const int blk = blockIdx.x;
    __shared__ float tile[32][33];

    if (blk < 500) {
        // ---- Wb transpose arm: (k, e-tile), dt loop inside ----
        int k = blk / 10, et = blk % 10;
        int tx = threadIdx.x & 31, ty = threadIdx.x >> 5;
        for (int dt = 0; dt < 10; ++dt) {
#pragma unroll
            for (int rr = 0; rr < 4; ++rr) {
                int d = dt * 32 + ty + rr * 8;
                int e = et * 32 + tx;
                tile[ty + rr * 8][tx] = (d < DDIM && e < DDIM) ? Wb[((size_t)k * DDIM + d) * DDIM + e] : 0.f;
            }
            __syncthreads();
#pragma unroll
            for (int rr = 0; rr < 4; ++rr) {
                int e = et * 32 + ty + rr * 8;     // global e'
                int d = dt * 32 + tx;
                size_t off = (size_t)k * WBT_K + (size_t)et * WTILE_E
                           + (size_t)(e & 31) * 320 + (size_t)(d ^ ((e & 7) << 3));
                wbt[off] = f2bf(tile[tx][ty + rr * 8]);
            }
            __syncthreads();
        }
        return;
    }
    // ---- projection + conversion arm: 512 blocks, 16 rows each ----
    int bid = blk - 500;
    const int kk = threadIdx.x & 63;
    const int grp = threadIdx.x >> 6;
    const int kks = kk < KDIM ? kk : 0;
    const float* src; int woff; float *dd, *dg; int r0;
    int ise2;
    int rowbase = bid * 16;
    if (rowbase < 4096) { r0 = rowbase; src = e1; woff = 0; dd = p1d; dg = p1g; ise2 = 0; }
    else { r0 = rowbase - 4096; src = e2; woff = DDIM; dd = p2d; dg = p2g; ise2 = 1; }
    const float* e0 = src + (size_t)(r0 + grp * 4) * DDIM;
    const float* wdp = Wd + (size_t)woff * KDIM + kks;
    const float* wgp = Wg + (size_t)woff * KDIM + kks;

    float ad[4] = {0.f, 0.f, 0.f, 0.f}, ag[4] = {0.f, 0.f, 0.f, 0.f};
    for (int c = 0; c < DDIM / 4; ++c) {
        const int d0 = c * 4;
        float4 x[4];
#pragma unroll
        for (int rr = 0; rr < 4; ++rr)
            x[rr] = *(const float4*)(e0 + (size_t)rr * DDIM + d0);
        float wd0 = wdp[(size_t)(d0 + 0) * KDIM];
        float wd1 = wdp[(size_t)(d0 + 1) * KDIM];
        float wd2 = wdp[(size_t)(d0 + 2) * KDIM];
        float wd3 = wdp[(size_t)(d0 + 3) * KDIM];
        float wg0 = wgp[(size_t)(d0 + 0) * KDIM];
        float wg1 = wgp[(size_t)(d0 + 1) * KDIM];
        float wg2 = wgp[(size_t)(d0 + 2) * KDIM];
        float wg3 = wgp[(size_t)(d0 + 3) * KDIM];
#pragma unroll
        for (int rr = 0; rr < 4; ++rr) {
            ad[rr] += x[rr].x * wd0 + x[rr].y * wd1 + x[rr].z * wd2 + x[rr].w * wd3;
            ag[rr] += x[rr].x * wg0 + x[rr].y * wg1 + x[rr].z * wg2 + x[rr].w * wg3;
        }
    }
    if (kk < KDIM) {
#pragma unroll
        for (int rr = 0; rr < 4; ++rr) {
            size_t o = (size_t)(r0 + grp * 4 + rr) * KDIM + kk;
            dd[o] = ad[rr];
            dg[o] = ag[rr];
        }
    }
    // conversion: this block's 16 rows -> bf16 (640 granules of 8)
    for (int it = 0; it < 3; ++it) {
        int g = threadIdx.x + it * 256;
        if (g >= 640) break;
        int rl = g / 40, d0 = (g % 40) * 8;
        const float* sp = src + (size_t)(r0 + rl) * DDIM;
        float v[8];
        if (d0 + 8 <= DDIM) {
            float4 lo = *(const float4*)(sp + d0);
            float4 hi = *(const float4*)(sp + d0 + 4);
            v[0] = lo.x; v[1] = lo.y; v[2] = lo.z; v[3] = lo.w;
            v[4] = hi.x; v[5] = hi.y; v[6] = hi.z; v[7] = hi.w;
        } else if (d0 < DDIM) {          // d0 == 296
            float4 lo = *(const float4*)(sp + d0);
            v[0] = lo.x; v[1] = lo.y; v[2] = lo.z; v[3] = lo.w;
            v[4] = v[5] = v[6] = v[7] = 0.f;
        } else {
            for (int j = 0; j < 8; ++j) v[j] = 0.f;
        }
        unsigned short tmp[8];
#pragma unroll
        for (int j = 0; j < 8; ++j) tmp[j] = f2bf(v[j]);
        unsigned short* dp;
        int row = r0 + rl;
        if (!ise2) {
            dp = e1b + (size_t)row * DP + d0;                      // row-major padded
        } else {
            int bb2 = row >> 7, j = row & 127;
            int g8 = d0 >> 3, et = g8 >> 2, gg = g8 & 3;
            dp = e2til + (((size_t)(bb2 * 10 + et) * 4 + gg) * 128 + j) * 8;
        }
        *(short8*)dp = *(short8*)tmp;
    }
}

// ---------- main: per (b,k): S = (e1 Wb[k]) e2^T, gate ----------
// R4: latency-exposure attack (R3 post-mortem: ~90% stall, all pipes idle).
//  F: XCD-contiguous k mapping. lid&7 = XCD (round-robin dispatch heuristic);
//     rank = xcd*200 + (lid>>3); k = rank/32, b = rank%32 -> all 32 blocks of
//     a k co-resident on ONE XCD; wbt slab (200KB) fetched from HBM once,
//     L2-hit for the rest. Barrier vmcnt drain sees ~200cy, not ~900cy.
//  E: e2 fragments staged to LDS by global_load_lds from the tiled e2til
//     layout; phase-2 B-frags = conflict-free ds_read_b128 of the CURRENT
//     slot, issued right after the barrier (zero global latency in-loop).
//  Register budget (R1/R2 lesson): af 80 + S 64A + t 32A + b0/b1 16+16 ~ 220.
template <int SLAB>
__global__ __launch_bounds__(256, 2) void grn_main(
    const unsigned short* __restrict__ e1b, const unsigned short* __restrict__ e2til,
    const unsigned short* __restrict__ wbt,
    const float* __restrict__ p1d, const float* __restrict__ p1g,
    const float* __restrict__ p2d, const float* __restrict__ p2g,
    const float* __restrict__ bg, const float* __restrict__ bb,
    const float* __restrict__ u, float* __restrict__ out, _Float16* __restrict__ slab) {
    const int lid = blockIdx.x + NB * blockIdx.y;   // 0..1599, x fastest
    const int rank = (lid & 7) * 200 + (lid >> 3);  // XCD-contiguous ranks
    const int k = rank >> 5, b = rank & 31;
    const int tid = threadIdx.x;
    const int wid = tid >> 6, lane = tid & 63;
    const int l32 = lane & 31, hi = lane >> 5;
    const int rw0 = wid * 32;                      // wave owns i-rows [rw0, rw0+32)

    __shared__ __align__(16) unsigned short wtile[2][WTILE_E];   // 2 x 20480B
    __shared__ __align__(16) unsigned short e2s[2][E2TILE_E];    // 2 x 8192B
    __shared__ float pbuf[4][128];

    const unsigned short* wsrc = wbt + (size_t)k * WBT_K;
    const unsigned short* esrc = e2til + (size_t)b * (10 * E2TILE_E);

    // prologue: stage tile 0 (wtile: 5 chunks/thread; e2s: 2 chunks/thread)
#pragma unroll
    for (int it = 0; it < 5; ++it) {
        int c = wid * 5 + it;
        gload_lds16(wsrc + c * 512 + lane * 8, &wtile[0][c * 512]);
    }
#pragma unroll
    for (int it = 0; it < 2; ++it) {
        int c = wid * 2 + it;
        gload_lds16(esrc + c * 512 + lane * 8, &e2s[0][c * 512]);
    }

    if (tid < 128) {
        int gi = (b * LL + tid) * KDIM + k;
        pbuf[0][tid] = p1d[gi];
        pbuf[1][tid] = p1g[gi];
        pbuf[2][tid] = p2d[gi];
        pbuf[3][tid] = p2g[gi];
    }
    const float u_k = u[k], bg_k = bg[k], b_k = bb[k];

    // e1 B-fragments (phase1): lane holds e1[i=rw0+l32][d=c*16+hi*8+j], c=0..19
    short8 af[20];
    {
        const unsigned short* p = e1b + ((size_t)(b * LL + rw0 + l32)) * DP + hi * 8;
#pragma unroll
        for (int c = 0; c < 20; ++c)
            af[c] = *(const short8*)(p + c * 16);
    }

    float16v S[4];
#pragma unroll
    for (int jt = 0; jt < 4; ++jt)
#pragma unroll
        for (int z = 0; z < 16; ++z) S[jt][z] = 0.f;

    const int swz = (l32 & 7) << 3;                 // phase1 read swizzle (elems)
    const int ebo = hi * 1024 + l32 * 8;            // e2s frag base (elems)

    __syncthreads();                                 // tile0 + pbuf ready

    for (int et = 0; et < 10; ++et) {
        const int cur = et & 1;
        // ks0 B-frags from LDS (current slot; conflict-free, zero ext latency)
        short8 b0[4];
#pragma unroll
        for (int jt = 0; jt < 4; ++jt)
            b0[jt] = *(const short8*)&e2s[cur][ebo + jt * 256];

        // stage next tile slot (drained by next barrier's vmcnt)
        if (et < 9) {
            const unsigned short* ws = wsrc + (et + 1) * WTILE_E;
            const unsigned short* es = esrc + (et + 1) * E2TILE_E;
            unsigned short* wl = &wtile[cur ^ 1][0];
            unsigned short* el = &e2s[cur ^ 1][0];
#pragma unroll
            for (int it = 0; it < 5; ++it) {
                int c = wid * 5 + it;
                gload_lds16(ws + c * 512 + lane * 8, wl + c * 512);
            }
#pragma unroll
            for (int it = 0; it < 2; ++it) {
                int c = wid * 2 + it;
                gload_lds16(es + c * 512 + lane * 8, el + c * 512);
            }
        }

        // phase 1 (mfma32): C[m=e'][n=i] = sum_d Wb[e'][d]*e1[i][d]
        const unsigned short* wt = &wtile[cur][l32 * 320];
        float16v t0, t1;
#pragma unroll
        for (int z = 0; z < 16; ++z) { t0[z] = 0.f; t1[z] = 0.f; }
#pragma unroll
        for (int c = 0; c < 20; c += 2) {
            short8 wa0 = *(const short8*)(wt + ((c * 16 + hi * 8) ^ swz));
            short8 wa1 = *(const short8*)(wt + (((c + 1) * 16 + hi * 8) ^ swz));
            t0 = mfma32(wa0, af[c], t0);
            t1 = mfma32(wa1, af[c + 1], t1);
        }
        // ks1 B-frags (LDS; cover = pack/swap + ks0 MFMAs)
        short8 b1[4];
#pragma unroll
        for (int jt = 0; jt < 4; ++jt)
            b1[jt] = *(const short8*)&e2s[cur][ebo + 2048 + jt * 256];

        float16v tt = t0 + t1;
        // pack to bf16 pairs; lane (l32,hi) holds T[i=l32][e'=(r&3)+8*(r>>2)+4*hi]
        unsigned int P0 = cvtpk(tt[0], tt[1]);
        unsigned int P1 = cvtpk(tt[2], tt[3]);
        unsigned int P2 = cvtpk(tt[4], tt[5]);
        unsigned int P3 = cvtpk(tt[6], tt[7]);
        unsigned int P4 = cvtpk(tt[8], tt[9]);
        unsigned int P5 = cvtpk(tt[10], tt[11]);
        unsigned int P6 = cvtpk(tt[12], tt[13]);
        unsigned int P7 = cvtpk(tt[14], tt[15]);
        // half-wave exchange: dst'={dst_lo,src_lo}, src'={dst_hi,src_hi}
        int2v r02 = __builtin_amdgcn_permlane32_swap((int)P0, (int)P2, false, false);
        int2v r13 = __builtin_amdgcn_permlane32_swap((int)P1, (int)P3, false, false);
        int2v r46 = __builtin_amdgcn_permlane32_swap((int)P4, (int)P6, false, false);
        int2v r57 = __builtin_amdgcn_permlane32_swap((int)P5, (int)P7, false, false);
        short8 A0 = __builtin_bit_cast(short8, (int4v){r02[0], r13[0], r02[1], r13[1]});
        short8 A1 = __builtin_bit_cast(short8, (int4v){r46[0], r57[0], r46[1], r57[1]});
        // phase 2 (mfma32): S[i][j] += sum_e' T[i][e'] * e2[j][e']
#pragma unroll
        for (int jt = 0; jt < 4; ++jt)
            S[jt] = mfma32(A0, b0[jt], S[jt]);
#pragma unroll
        for (int jt = 0; jt < 4; ++jt)
            S[jt] = mfma32(A1, b1[jt], S[jt]);

        __syncthreads();   // publishes next tile (vmcnt drain) / guards dbuf reuse
    }

    // epilogue: gate, mix, scale by u[k]
    // S[jt][r]: i = rw0 + (r&3)+8*(r>>2)+4*hi, j = jt*32 + l32
    float pdj[4], pgj[4];
#pragma unroll
    for (int jt = 0; jt < 4; ++jt) {
        pdj[jt] = pbuf[2][jt * 32 + l32];
        pgj[jt] = pbuf[3][jt * 32 + l32] + bg_k;
    }
    _Float16* sdst = slab + ((size_t)k * NB + b) * 16384;
    float* adst = out + (size_t)b * LL * LL;
#pragma unroll
    for (int r = 0; r < 16; ++r) {
        int i = rw0 + (r & 3) + 8 * (r >> 2) + 4 * hi;
        float pdi_ = pbuf[0][i];
        float pgi_ = pbuf[1][i];
#pragma unroll
        for (int jt = 0; jt < 4; ++jt) {
            float btp = S[jt][r];
            float sd = pdi_ + pdj[jt];
            float sg = pgi_ + pgj[jt];
            float e2x = __expf(2.f * sd);
            float sln = 1.f - 2.f * __builtin_amdgcn_rcpf(e2x + 1.f);   // tanh(sd)
            float g = __builtin_amdgcn_rcpf(1.f + __expf(-sg));          // sigmoid(sg)
            float val = u_k * (g * btp + (1.f - g) * sln + b_k);
            if (SLAB) {
                // permuted coalesced layout: pos = v*256 + tid, v = jt*16 + r
                sdst[(jt * 16 + r) * 256 + tid] = (_Float16)val;
            } else {
                unsafeAtomicAdd(adst + (size_t)i * LL + (jt * 32 + l32), val);
            }
        }
    }
}

// ---------- reduce: out[b][i][j] = sum_k slab[k][b][pos]; decode permutation ----------
__global__ void reduce_k(const _Float16* __restrict__ slab, float* __restrict__ out) {
    int idx = blockIdx.x * 256 + threadIdx.x;     // 0..131071
    int b = idx >> 12;
    int p4 = idx & 4095;
    int pos0 = p4 * 4;
    int v = pos0 >> 8, tid0 = pos0 & 255;
    int jt = v >> 4, r = v & 15;
    int wid = tid0 >> 6, lane = tid0 & 63, hi2 = lane >> 5, l32 = lane & 31;
    int i = wid * 32 + (r & 3) + 8 * (r >> 2) + 4 * hi2;
    int j0 = jt * 32 + l32;

    float a0 = 0.f, a1 = 0.f, a2 = 0.f, a3 = 0.f;
    const _Float16* sp = slab + (size_t)b * 16384 + pos0;
#pragma unroll
    for (int k = 0; k < KDIM; ++k) {
        half4v h = *(const half4v*)(sp + (size_t)k * (NB * 16384));
        a0 += (float)h[0]; a1 += (float)h[1]; a2 += (float)h[2]; a3 += (float)h[3];
    }
    float4 rv; rv.x = a0; rv.y = a1; rv.z = a2; rv.w = a3;
    *(float4*)(out + (size_t)b * 16384 + i * 128 + j0) = rv;
}

extern "C" void kernel_launch(void* const* d_in, const int* in_sizes, int n_in,
                              void* d_out, int out_size, void* d_ws, size_t ws_size,
                              hipStream_t stream) {
    const float* e1 = (const float*)d_in[0];   // (32,128,300)
    const float* e2 = (const float*)d_in[1];   // (32,128,300)
    const float* Wb = (const float*)d_in[2];   // (50,300,300)
    const float* Wd = (const float*)d_in[3];   // (600,50)
    const float* Wg = (const float*)d_in[4];   // (600,50)
    const float* bg = (const float*)d_in[5];   // (50,)
    const float* bb = (const float*)d_in[6];   // (50,)
    const float* u  = (const float*)d_in[7];   // (50,1)
    float* out = (float*)d_out;                // (32,128,128,1)

    unsigned short* e1b   = (unsigned short*)d_ws;               // 1,310,720 elems
    unsigned short* e2til = e1b + 1310720;                       // 1,310,720 elems (tiled)
    unsigned short* wbt   = e2til + 1310720;                     // 5,120,000 elems
    float* pf  = (float*)((char*)d_ws + 15482880);
    float* p1d = pf;
    float* p1g = pf + 204800;
    float* p2d = pf + 409600;
    float* p2g = pf + 614400;                                    // end 18,759,680 B
    _Float16* slab = (_Float16*)((char*)d_ws + SLAB_OFF);        // 50x32x16384 halves

    prep_all<<<1012, 256, 0, stream>>>(e1, e2, Wb, Wd, Wg,
                                       e1b, e2til, wbt,
                                       p1d, p1g, p2d, p2g);

    if (ws_size >= WS_NEED) {
        grn_main<1><<<dim3(NB, KDIM), 256, 0, stream>>>(e1b, e2til, wbt,
                                                        p1d, p1g, p2d, p2g,
                                                        bg, bb, u, out, slab);
        reduce_k<<<512, 256, 0, stream>>>(slab, out);
    } else {
        hipMemsetAsync(d_out, 0, (size_t)out_size * sizeof(float), stream);
        grn_main<0><<<dim3(NB, KDIM), 256, 0, stream>>>(e1b, e2til, wbt,
                                                        p1d, p1g, p2d, p2g,
                                                        bg, bb, u, out, slab);
    }
}

// Round 5
// 215.423 us; speedup vs baseline: 1.3767x; 1.0717x over previous
//
#include <hip/hip_runtime.h>
#include <hip/hip_bf16.h>

typedef __attribute__((ext_vector_type(8))) short short8;
typedef __attribute__((ext_vector_type(16))) float float16v;
typedef __attribute__((ext_vector_type(4))) int int4v;
typedef __attribute__((ext_vector_type(2))) int int2v;
typedef _Float16 half4v __attribute__((ext_vector_type(4)));

#define NB 32
#define LL 128
#define DDIM 300
#define DP 320
#define KDIM 50
#define WTILE_E 10240            // elems per (k, et) wtile: 32 rows x 320
#define WBT_K   102400           // elems per k (10 tiles)
#define E2TILE_E 4096            // elems per (b, et) e2 tile: 4 granules x 128 j x 8
#define SLAB_OFF 18759680ull
#define SLAB_BYTES (50ull * 32ull * 16384ull * 2ull)          // 52,428,800
#define WS_NEED  (SLAB_OFF + SLAB_BYTES)

__device__ __forceinline__ unsigned short f2bf(float x) {
    unsigned int u = __float_as_uint(x);
    unsigned int r = (u + 0x7FFFu + ((u >> 16) & 1u)) >> 16;
    return (unsigned short)r;
}
__device__ __forceinline__ float16v mfma32(short8 a, short8 b, float16v c) {
    return __builtin_amdgcn_mfma_f32_32x32x16_bf16(a, b, c, 0, 0, 0);
}
__device__ __forceinline__ unsigned int cvtpk(float lo, float hi) {
    unsigned int r;
    asm("v_cvt_pk_bf16_f32 %0, %1, %2" : "=v"(r) : "v"(lo), "v"(hi));
    return r;
}
__device__ __forceinline__ void gload_lds16(const void* g, void* l) {
    __builtin_amdgcn_global_load_lds((const __attribute__((address_space(1))) void*)g,
                                     (__attribute__((address_space(3))) void*)l, 16, 0, 0);
}

// ---------- fused prep: [0,500) Wb->Wbt arm; [500,1012) projections+convert arm ----------
// Wbt layout: per (k, et) a LINEAR 20480B tile, XOR swizzle pre-applied:
//   elem offset = k*102400 + et*10240 + (e&31)*320 + (d ^ ((e&7)<<3))
// e2til layout: per (b, et) a LINEAR 8192B tile, granule-major:
//   elem offset = ((b*10 + et)*4 + g)*1024 + j*8 + jj     (g = e'granule 0..3)
// Both staged with global_load_lds (linear dest).
__global__ void prep_all(const float* __restrict__ e1, const float* __restrict__ e2,
                         const float* __restrict__ Wb,
                         const float* __restrict__ Wd, const float* __restrict__ Wg,
                         unsigned short* __restrict__ e1b, unsigned short* __restrict__ e2til,
                         unsigned short* __restrict__ wbt,
                         float* __restrict__ p1d, float* __restrict__ p1g,
                         float* __restrict__ p2d, float* __restrict__ p2g) {
    const int blk = blockIdx.x;
    __shared__ float tile[32][33];

    if (blk < 500) {
        // ---- Wb transpose arm: (k, e-tile), dt loop inside ----
        int k = blk / 10, et = blk % 10;
        int tx = threadIdx.x & 31, ty = threadIdx.x >> 5;
        for (int dt = 0; dt < 10; ++dt) {
#pragma unroll
            for (int rr = 0; rr < 4; ++rr) {
                int d = dt * 32 + ty + rr * 8;
                int e = et * 32 + tx;
                tile[ty + rr * 8][tx] = (d < DDIM && e < DDIM) ? Wb[((size_t)k * DDIM + d) * DDIM + e] : 0.f;
            }
            __syncthreads();
#pragma unroll
            for (int rr = 0; rr < 4; ++rr) {
                int e = et * 32 + ty + rr * 8;     // global e'
                int d = dt * 32 + tx;
                size_t off = (size_t)k * WBT_K + (size_t)et * WTILE_E
                           + (size_t)(e & 31) * 320 + (size_t)(d ^ ((e & 7) << 3));
                wbt[off] = f2bf(tile[tx][ty + rr * 8]);
            }
            __syncthreads();
        }
        return;
    }
    // ---- projection + conversion arm: 512 blocks, 16 rows each ----
    int bid = blk - 500;
    const int kk = threadIdx.x & 63;
    const int grp = threadIdx.x >> 6;
    const int kks = kk < KDIM ? kk : 0;
    const float* src; int woff; float *dd, *dg; int r0;
    int ise2;
    int rowbase = bid * 16;
    if (rowbase < 4096) { r0 = rowbase; src = e1; woff = 0; dd = p1d; dg = p1g; ise2 = 0; }
    else { r0 = rowbase - 4096; src = e2; woff = DDIM; dd = p2d; dg = p2g; ise2 = 1; }
    const float* e0 = src + (size_t)(r0 + grp * 4) * DDIM;
    const float* wdp = Wd + (size_t)woff * KDIM + kks;
    const float* wgp = Wg + (size_t)woff * KDIM + kks;

    float ad[4] = {0.f, 0.f, 0.f, 0.f}, ag[4] = {0.f, 0.f, 0.f, 0.f};
    for (int c = 0; c < DDIM / 4; ++c) {
        const int d0 = c * 4;
        float4 x[4];
#pragma unroll
        for (int rr = 0; rr < 4; ++rr)
            x[rr] = *(const float4*)(e0 + (size_t)rr * DDIM + d0);
        float wd0 = wdp[(size_t)(d0 + 0) * KDIM];
        float wd1 = wdp[(size_t)(d0 + 1) * KDIM];
        float wd2 = wdp[(size_t)(d0 + 2) * KDIM];
        float wd3 = wdp[(size_t)(d0 + 3) * KDIM];
        float wg0 = wgp[(size_t)(d0 + 0) * KDIM];
        float wg1 = wgp[(size_t)(d0 + 1) * KDIM];
        float wg2 = wgp[(size_t)(d0 + 2) * KDIM];
        float wg3 = wgp[(size_t)(d0 + 3) * KDIM];
#pragma unroll
        for (int rr = 0; rr < 4; ++rr) {
            ad[rr] += x[rr].x * wd0 + x[rr].y * wd1 + x[rr].z * wd2 + x[rr].w * wd3;
            ag[rr] += x[rr].x * wg0 + x[rr].y * wg1 + x[rr].z * wg2 + x[rr].w * wg3;
        }
    }
    if (kk < KDIM) {
#pragma unroll
        for (int rr = 0; rr < 4; ++rr) {
            size_t o = (size_t)(r0 + grp * 4 + rr) * KDIM + kk;
            dd[o] = ad[rr];
            dg[o] = ag[rr];
        }
    }
    // conversion: this block's 16 rows -> bf16 (640 granules of 8)
    for (int it = 0; it < 3; ++it) {
        int g = threadIdx.x + it * 256;
        if (g >= 640) break;
        int rl = g / 40, d0 = (g % 40) * 8;
        const float* sp = src + (size_t)(r0 + rl) * DDIM;
        float v[8];
        if (d0 + 8 <= DDIM) {
            float4 lo = *(const float4*)(sp + d0);
            float4 hi = *(const float4*)(sp + d0 + 4);
            v[0] = lo.x; v[1] = lo.y; v[2] = lo.z; v[3] = lo.w;
            v[4] = hi.x; v[5] = hi.y; v[6] = hi.z; v[7] = hi.w;
        } else if (d0 < DDIM) {          // d0 == 296
            float4 lo = *(const float4*)(sp + d0);
            v[0] = lo.x; v[1] = lo.y; v[2] = lo.z; v[3] = lo.w;
            v[4] = v[5] = v[6] = v[7] = 0.f;
        } else {
            for (int j = 0; j < 8; ++j) v[j] = 0.f;
        }
        unsigned short tmp[8];
#pragma unroll
        for (int j = 0; j < 8; ++j) tmp[j] = f2bf(v[j]);
        unsigned short* dp;
        int row = r0 + rl;
        if (!ise2) {
            dp = e1b + (size_t)row * DP + d0;                      // row-major padded
        } else {
            int bb2 = row >> 7, j = row & 127;
            int g8 = d0 >> 3, et = g8 >> 2, gg = g8 & 3;
            dp = e2til + (((size_t)(bb2 * 10 + et) * 4 + gg) * 128 + j) * 8;
        }
        *(short8*)dp = *(short8*)tmp;
    }
}

// ---------- main: per (b,k): S = (e1 Wb[k]) e2^T, gate ----------
// R5: (a) F-remap REVERTED (R4 post-mortem: FETCH 53->142MB; lid&7!=XCD; the
//     identity map's time-locality of k is the better L2 scheme).
//     (b) counted-vmcnt pipeline (T3/T4): wtile 3-deep (60KB), e2s 2-deep;
//     iter n issues e2s(n+1) THEN wtile(n+2); barrier is raw s_barrier with
//     s_waitcnt vmcnt(5) -- wtile(n+2)'s 5 loads stay in flight across the
//     barrier, so the wait covers only loads issued >=1 iteration ago.
//     Issue order e2s-before-wtile is correctness-critical (vmcnt waits for
//     all but the NEWEST N) -> pinned with sched_barrier(0).
//     LDS: 60K wtile + 16K e2s + 2K pbuf = 78KB -> still 2 blocks/CU.
//     Registers unchanged (R1/R2 lesson: 2-block unified-RF cap is binding).
template <int SLAB>
__global__ __launch_bounds__(256, 2) void grn_main(
    const unsigned short* __restrict__ e1b, const unsigned short* __restrict__ e2til,
    const unsigned short* __restrict__ wbt,
    const float* __restrict__ p1d, const float* __restrict__ p1g,
    const float* __restrict__ p2d, const float* __restrict__ p2g,
    const float* __restrict__ bg, const float* __restrict__ bb,
    const float* __restrict__ u, float* __restrict__ out, _Float16* __restrict__ slab) {
    const int b = blockIdx.x, k = blockIdx.y;
    const int tid = threadIdx.x;
    const int wid = tid >> 6, lane = tid & 63;
    const int l32 = lane & 31, hi = lane >> 5;
    const int rw0 = wid * 32;                      // wave owns i-rows [rw0, rw0+32)

    __shared__ __align__(16) unsigned short wtile[3][WTILE_E];   // 3 x 20480B
    __shared__ __align__(16) unsigned short e2s[2][E2TILE_E];    // 2 x 8192B
    __shared__ float pbuf[4][128];

    const unsigned short* wsrc = wbt + (size_t)k * WBT_K;
    const unsigned short* esrc = e2til + (size_t)b * (10 * E2TILE_E);

    // prologue stage: e2s(0), wtile(0) first (oldest -> drained by vmcnt(5))
#pragma unroll
    for (int it = 0; it < 2; ++it) {
        int c = wid * 2 + it;
        gload_lds16(esrc + c * 512 + lane * 8, &e2s[0][c * 512]);
    }
#pragma unroll
    for (int it = 0; it < 5; ++it) {
        int c = wid * 5 + it;
        gload_lds16(wsrc + c * 512 + lane * 8, &wtile[0][c * 512]);
    }

    if (tid < 128) {
        int gi = (b * LL + tid) * KDIM + k;
        pbuf[0][tid] = p1d[gi];
        pbuf[1][tid] = p1g[gi];
        pbuf[2][tid] = p2d[gi];
        pbuf[3][tid] = p2g[gi];
    }
    const float u_k = u[k], bg_k = bg[k], b_k = bb[k];

    // e1 B-fragments (phase1): lane holds e1[i=rw0+l32][d=c*16+hi*8+j], c=0..19
    short8 af[20];
    {
        const unsigned short* p = e1b + ((size_t)(b * LL + rw0 + l32)) * DP + hi * 8;
#pragma unroll
        for (int c = 0; c < 20; ++c)
            af[c] = *(const short8*)(p + c * 16);
    }

    float16v S[4];
#pragma unroll
    for (int jt = 0; jt < 4; ++jt)
#pragma unroll
        for (int z = 0; z < 16; ++z) S[jt][z] = 0.f;

    const int swz = (l32 & 7) << 3;                 // phase1 read swizzle (elems)
    const int ebo = hi * 1024 + l32 * 8;            // e2s frag base (elems)

    // prologue stage: wtile(1) LAST (the 5 loads vmcnt(5) leaves in flight)
    __builtin_amdgcn_sched_barrier(0);
#pragma unroll
    for (int it = 0; it < 5; ++it) {
        int c = wid * 5 + it;
        gload_lds16(wsrc + WTILE_E + c * 512 + lane * 8, &wtile[1][c * 512]);
    }
    asm volatile("s_waitcnt vmcnt(5)" ::: "memory");
    __builtin_amdgcn_s_barrier();
    __builtin_amdgcn_sched_barrier(0);

#pragma unroll
    for (int et = 0; et < 10; ++et) {
        const int wr = et % 3;                     // literal (unrolled)
        const int er = et & 1;
        // ks0 B-frags from LDS (current slot)
        short8 b0[4];
#pragma unroll
        for (int jt = 0; jt < 4; ++jt)
            b0[jt] = *(const short8*)&e2s[er][ebo + jt * 256];

        // stage e2s(et+1) FIRST, then wtile(et+2): vmcnt(5) leaves only the
        // wtile(et+2) loads outstanding across the barrier.
        if (et < 9) {
            const unsigned short* es = esrc + (et + 1) * E2TILE_E;
            unsigned short* el = &e2s[er ^ 1][0];
#pragma unroll
            for (int it = 0; it < 2; ++it) {
                int c = wid * 2 + it;
                gload_lds16(es + c * 512 + lane * 8, el + c * 512);
            }
        }
        __builtin_amdgcn_sched_barrier(0);          // pin e2s-before-wtile order
        if (et < 8) {
            const unsigned short* ws = wsrc + (et + 2) * WTILE_E;
            unsigned short* wl = &wtile[(et + 2) % 3][0];
#pragma unroll
            for (int it = 0; it < 5; ++it) {
                int c = wid * 5 + it;
                gload_lds16(ws + c * 512 + lane * 8, wl + c * 512);
            }
        }

        // phase 1 (mfma32): C[m=e'][n=i] = sum_d Wb[e'][d]*e1[i][d]
        const unsigned short* wt = &wtile[wr][l32 * 320];
        float16v t0, t1;
#pragma unroll
        for (int z = 0; z < 16; ++z) { t0[z] = 0.f; t1[z] = 0.f; }
#pragma unroll
        for (int c = 0; c < 20; c += 2) {
            short8 wa0 = *(const short8*)(wt + ((c * 16 + hi * 8) ^ swz));
            short8 wa1 = *(const short8*)(wt + (((c + 1) * 16 + hi * 8) ^ swz));
            t0 = mfma32(wa0, af[c], t0);
            t1 = mfma32(wa1, af[c + 1], t1);
        }
        // ks1 B-frags (LDS; cover = pack/swap + ks0 MFMAs)
        short8 b1[4];
#pragma unroll
        for (int jt = 0; jt < 4; ++jt)
            b1[jt] = *(const short8*)&e2s[er][ebo + 2048 + jt * 256];

        float16v tt = t0 + t1;
        // pack to bf16 pairs; lane (l32,hi) holds T[i=l32][e'=(r&3)+8*(r>>2)+4*hi]
        unsigned int P0 = cvtpk(tt[0], tt[1]);
        unsigned int P1 = cvtpk(tt[2], tt[3]);
        unsigned int P2 = cvtpk(tt[4], tt[5]);
        unsigned int P3 = cvtpk(tt[6], tt[7]);
        unsigned int P4 = cvtpk(tt[8], tt[9]);
        unsigned int P5 = cvtpk(tt[10], tt[11]);
        unsigned int P6 = cvtpk(tt[12], tt[13]);
        unsigned int P7 = cvtpk(tt[14], tt[15]);
        // half-wave exchange: dst'={dst_lo,src_lo}, src'={dst_hi,src_hi}
        int2v r02 = __builtin_amdgcn_permlane32_swap((int)P0, (int)P2, false, false);
        int2v r13 = __builtin_amdgcn_permlane32_swap((int)P1, (int)P3, false, false);
        int2v r46 = __builtin_amdgcn_permlane32_swap((int)P4, (int)P6, false, false);
        int2v r57 = __builtin_amdgcn_permlane32_swap((int)P5, (int)P7, false, false);
        short8 A0 = __builtin_bit_cast(short8, (int4v){r02[0], r13[0], r02[1], r13[1]});
        short8 A1 = __builtin_bit_cast(short8, (int4v){r46[0], r57[0], r46[1], r57[1]});
        // phase 2 (mfma32): S[i][j] += sum_e' T[i][e'] * e2[j][e']
#pragma unroll
        for (int jt = 0; jt < 4; ++jt)
            S[jt] = mfma32(A0, b0[jt], S[jt]);
#pragma unroll
        for (int jt = 0; jt < 4; ++jt)
            S[jt] = mfma32(A1, b1[jt], S[jt]);

        // counted-vmcnt barrier: wtile(et+2) stays in flight (T4).
        if (et < 8) {
            asm volatile("s_waitcnt vmcnt(5)" ::: "memory");
        } else if (et == 8) {
            asm volatile("s_waitcnt vmcnt(0)" ::: "memory");
        }
        if (et < 9) {
            __builtin_amdgcn_s_barrier();
            __builtin_amdgcn_sched_barrier(0);
        }
    }

    // epilogue: gate, mix, scale by u[k]
    // S[jt][r]: i = rw0 + (r&3)+8*(r>>2)+4*hi, j = jt*32 + l32
    float pdj[4], pgj[4];
#pragma unroll
    for (int jt = 0; jt < 4; ++jt) {
        pdj[jt] = pbuf[2][jt * 32 + l32];
        pgj[jt] = pbuf[3][jt * 32 + l32] + bg_k;
    }
    _Float16* sdst = slab + ((size_t)k * NB + b) * 16384;
    float* adst = out + (size_t)b * LL * LL;
#pragma unroll
    for (int r = 0; r < 16; ++r) {
        int i = rw0 + (r & 3) + 8 * (r >> 2) + 4 * hi;
        float pdi_ = pbuf[0][i];
        float pgi_ = pbuf[1][i];
#pragma unroll
        for (int jt = 0; jt < 4; ++jt) {
            float btp = S[jt][r];
            float sd = pdi_ + pdj[jt];
            float sg = pgi_ + pgj[jt];
            float e2x = __expf(2.f * sd);
            float sln = 1.f - 2.f * __builtin_amdgcn_rcpf(e2x + 1.f);   // tanh(sd)
            float g = __builtin_amdgcn_rcpf(1.f + __expf(-sg));          // sigmoid(sg)
            float val = u_k * (g * btp + (1.f - g) * sln + b_k);
            if (SLAB) {
                // permuted coalesced layout: pos = v*256 + tid, v = jt*16 + r
                sdst[(jt * 16 + r) * 256 + tid] = (_Float16)val;
            } else {
                unsafeAtomicAdd(adst + (size_t)i * LL + (jt * 32 + l32), val);
            }
        }
    }
}

// ---------- reduce: out[b][i][j] = sum_k slab[k][b][pos]; decode permutation ----------
__global__ void reduce_k(const _Float16* __restrict__ slab, float* __restrict__ out) {
    int idx = blockIdx.x * 256 + threadIdx.x;     // 0..131071
    int b = idx >> 12;
    int p4 = idx & 4095;
    int pos0 = p4 * 4;
    int v = pos0 >> 8, tid0 = pos0 & 255;
    int jt = v >> 4, r = v & 15;
    int wid = tid0 >> 6, lane = tid0 & 63, hi2 = lane >> 5, l32 = lane & 31;
    int i = wid * 32 + (r & 3) + 8 * (r >> 2) + 4 * hi2;
    int j0 = jt * 32 + l32;

    float a0 = 0.f, a1 = 0.f, a2 = 0.f, a3 = 0.f;
    const _Float16* sp = slab + (size_t)b * 16384 + pos0;
#pragma unroll
    for (int k = 0; k < KDIM; ++k) {
        half4v h = *(const half4v*)(sp + (size_t)k * (NB * 16384));
        a0 += (float)h[0]; a1 += (float)h[1]; a2 += (float)h[2]; a3 += (float)h[3];
    }
    float4 rv; rv.x = a0; rv.y = a1; rv.z = a2; rv.w = a3;
    *(float4*)(out + (size_t)b * 16384 + i * 128 + j0) = rv;
}

extern "C" void kernel_launch(void* const* d_in, const int* in_sizes, int n_in,
                              void* d_out, int out_size, void* d_ws, size_t ws_size,
                              hipStream_t stream) {
    const float* e1 = (const float*)d_in[0];   // (32,128,300)
    const float* e2 = (const float*)d_in[1];   // (32,128,300)
    const float* Wb = (const float*)d_in[2];   // (50,300,300)
    const float* Wd = (const float*)d_in[3];   // (600,50)
    const float* Wg = (const float*)d_in[4];   // (600,50)
    const float* bg = (const float*)d_in[5];   // (50,)
    const float* bb = (const float*)d_in[6];   // (50,)
    const float* u  = (const float*)d_in[7];   // (50,1)
    float* out = (float*)d_out;                // (32,128,128,1)

    unsigned short* e1b   = (unsigned short*)d_ws;               // 1,310,720 elems
    unsigned short* e2til = e1b + 1310720;                       // 1,310,720 elems (tiled)
    unsigned short* wbt   = e2til + 1310720;                     // 5,120,000 elems
    float* pf  = (float*)((char*)d_ws + 15482880);
    float* p1d = pf;
    float* p1g = pf + 204800;
    float* p2d = pf + 409600;
    float* p2g = pf + 614400;                                    // end 18,759,680 B
    _Float16* slab = (_Float16*)((char*)d_ws + SLAB_OFF);        // 50x32x16384 halves

    prep_all<<<1012, 256, 0, stream>>>(e1, e2, Wb, Wd, Wg,
                                       e1b, e2til, wbt,
                                       p1d, p1g, p2d, p2g);

    if (ws_size >= WS_NEED) {
        grn_main<1><<<dim3(NB, KDIM), 256, 0, stream>>>(e1b, e2til, wbt,
                                                        p1d, p1g, p2d, p2g,
                                                        bg, bb, u, out, slab);
        reduce_k<<<512, 256, 0, stream>>>(slab, out);
    } else {
        hipMemsetAsync(d_out, 0, (size_t)out_size * sizeof(float), stream);
        grn_main<0><<<dim3(NB, KDIM), 256, 0, stream>>>(e1b, e2til, wbt,
                                                        p1d, p1g, p2d, p2g,
                                                        bg, bb, u, out, slab);
    }
}

// Round 6
// 208.553 us; speedup vs baseline: 1.4220x; 1.0329x over previous
//
#include <hip/hip_runtime.h>
#include <hip/hip_bf16.h>

typedef __attribute__((ext_vector_type(8))) short short8;
typedef __attribute__((ext_vector_type(16))) float float16v;
typedef __attribute__((ext_vector_type(4))) int int4v;
typedef __attribute__((ext_vector_type(2))) int int2v;
typedef _Float16 half4v __attribute__((ext_vector_type(4)));

#define NB 32
#define LL 128
#define DDIM 300
#define DP 320
#define KDIM 50
#define WTILE_E 10240            // elems per (k, et) wtile: 32 rows x 320
#define WBT_K   102400           // elems per k (10 tiles)
#define E2TILE_E 4096            // elems per (b, et) e2 tile: 4 granules x 128 j x 8
#define SLAB_OFF 18759680ull
#define SLAB_BYTES (50ull * 32ull * 16384ull * 2ull)          // 52,428,800
#define WS_NEED  (SLAB_OFF + SLAB_BYTES)

__device__ __forceinline__ unsigned short f2bf(float x) {
    unsigned int u = __float_as_uint(x);
    unsigned int r = (u + 0x7FFFu + ((u >> 16) & 1u)) >> 16;
    return (unsigned short)r;
}
__device__ __forceinline__ float16v mfma32(short8 a, short8 b, float16v c) {
    return __builtin_amdgcn_mfma_f32_32x32x16_bf16(a, b, c, 0, 0, 0);
}
__device__ __forceinline__ unsigned int cvtpk(float lo, float hi) {
    unsigned int r;
    asm("v_cvt_pk_bf16_f32 %0, %1, %2" : "=v"(r) : "v"(lo), "v"(hi));
    return r;
}
__device__ __forceinline__ void gload_lds16(const void* g, void* l) {
    __builtin_amdgcn_global_load_lds((const __attribute__((address_space(1))) void*)g,
                                     (__attribute__((address_space(3))) void*)l, 16, 0, 0);
}

// ---------- fused prep: [0,1000) Wb->Wbt arm; [1000,1512) projections+convert arm ----------
// Wbt layout (unchanged since R3): per (k, et) a LINEAR 20480B tile, XOR swizzle
// pre-applied:  elem offset = k*102400 + et*10240 + (e&31)*320 + (d ^ ((e&7)<<3))
// R6: transpose arm rewritten -- writer gathers 8 consecutive d down an LDS
// column (stride-33, conflict-free) and emits ONE short8 store (the XOR only
// touches bits >=3, so 8 consecutive d stay contiguous). 8x fewer store
// instrs, fully coalesced. dt range split across 2 blocks (1000 blocks).
// e2til layout: per (b, et) a LINEAR 8192B tile, granule-major:
//   elem offset = ((b*10 + et)*4 + g)*1024 + j*8 + jj     (g = e'granule 0..3)
__global__ void prep_all(const float* __restrict__ e1, const float* __restrict__ e2,
                         const float* __restrict__ Wb,
                         const float* __restrict__ Wd, const float* __restrict__ Wg,
                         unsigned short* __restrict__ e1b, unsigned short* __restrict__ e2til,
                         unsigned short* __restrict__ wbt,
                         float* __restrict__ p1d, float* __restrict__ p1g,
                         float* __restrict__ p2d, float* __restrict__ p2g) {
    const int blk = blockIdx.x;
    __shared__ float tile[32][33];

    if (blk < 1000) {
        // ---- Wb transpose arm: (k, et, dt-half); 5 dt rounds ----
        int k = blk / 20, sub = blk % 20, et = sub >> 1, dh = sub & 1;
        int tx = threadIdx.x & 31, ty = threadIdx.x >> 5;
        const size_t obase = (size_t)k * WBT_K + (size_t)et * WTILE_E;
        for (int dt = dh * 5; dt < dh * 5 + 5; ++dt) {
#pragma unroll
            for (int rr = 0; rr < 4; ++rr) {
                int d = dt * 32 + ty + rr * 8;
                int e = et * 32 + tx;
                tile[ty + rr * 8][tx] = (d < DDIM && e < DDIM) ? Wb[((size_t)k * DDIM + d) * DDIM + e] : 0.f;
            }
            __syncthreads();
            if (threadIdx.x < 128) {
                int e_loc = threadIdx.x & 31, oct = threadIdx.x >> 5;   // oct 0..3
                int e7 = (et * 32 + e_loc) & 7;                         // == e_loc&7
                unsigned short tmp[8];
#pragma unroll
                for (int s = 0; s < 8; ++s)
                    tmp[s] = f2bf(tile[oct * 8 + s][e_loc]);
                int d0g = dt * 32 + oct * 8;
                size_t off = obase + (size_t)e_loc * 320 + (size_t)(d0g ^ (e7 << 3));
                *(short8*)&wbt[off] = *(short8*)tmp;
            }
            __syncthreads();
        }
        return;
    }
    // ---- projection + conversion arm: 512 blocks, 16 rows each ----
    int bid = blk - 1000;
    const int kk = threadIdx.x & 63;
    const int grp = threadIdx.x >> 6;
    const int kks = kk < KDIM ? kk : 0;
    const float* src; int woff; float *dd, *dg; int r0;
    int ise2;
    int rowbase = bid * 16;
    if (rowbase < 4096) { r0 = rowbase; src = e1; woff = 0; dd = p1d; dg = p1g; ise2 = 0; }
    else { r0 = rowbase - 4096; src = e2; woff = DDIM; dd = p2d; dg = p2g; ise2 = 1; }
    const float* e0 = src + (size_t)(r0 + grp * 4) * DDIM;
    const float* wdp = Wd + (size_t)woff * KDIM + kks;
    const float* wgp = Wg + (size_t)woff * KDIM + kks;

    float ad[4] = {0.f, 0.f, 0.f, 0.f}, ag[4] = {0.f, 0.f, 0.f, 0.f};
    for (int c = 0; c < DDIM / 4; ++c) {
        const int d0 = c * 4;
        float4 x[4];
#pragma unroll
        for (int rr = 0; rr < 4; ++rr)
            x[rr] = *(const float4*)(e0 + (size_t)rr * DDIM + d0);
        float wd0 = wdp[(size_t)(d0 + 0) * KDIM];
        float wd1 = wdp[(size_t)(d0 + 1) * KDIM];
        float wd2 = wdp[(size_t)(d0 + 2) * KDIM];
        float wd3 = wdp[(size_t)(d0 + 3) * KDIM];
        float wg0 = wgp[(size_t)(d0 + 0) * KDIM];
        float wg1 = wgp[(size_t)(d0 + 1) * KDIM];
        float wg2 = wgp[(size_t)(d0 + 2) * KDIM];
        float wg3 = wgp[(size_t)(d0 + 3) * KDIM];
#pragma unroll
        for (int rr = 0; rr < 4; ++rr) {
            ad[rr] += x[rr].x * wd0 + x[rr].y * wd1 + x[rr].z * wd2 + x[rr].w * wd3;
            ag[rr] += x[rr].x * wg0 + x[rr].y * wg1 + x[rr].z * wg2 + x[rr].w * wg3;
        }
    }
    if (kk < KDIM) {
#pragma unroll
        for (int rr = 0; rr < 4; ++rr) {
            size_t o = (size_t)(r0 + grp * 4 + rr) * KDIM + kk;
            dd[o] = ad[rr];
            dg[o] = ag[rr];
        }
    }
    // conversion: this block's 16 rows -> bf16 (640 granules of 8)
    for (int it = 0; it < 3; ++it) {
        int g = threadIdx.x + it * 256;
        if (g >= 640) break;
        int rl = g / 40, d0 = (g % 40) * 8;
        const float* sp = src + (size_t)(r0 + rl) * DDIM;
        float v[8];
        if (d0 + 8 <= DDIM) {
            float4 lo = *(const float4*)(sp + d0);
            float4 hi = *(const float4*)(sp + d0 + 4);
            v[0] = lo.x; v[1] = lo.y; v[2] = lo.z; v[3] = lo.w;
            v[4] = hi.x; v[5] = hi.y; v[6] = hi.z; v[7] = hi.w;
        } else if (d0 < DDIM) {          // d0 == 296
            float4 lo = *(const float4*)(sp + d0);
            v[0] = lo.x; v[1] = lo.y; v[2] = lo.z; v[3] = lo.w;
            v[4] = v[5] = v[6] = v[7] = 0.f;
        } else {
            for (int j = 0; j < 8; ++j) v[j] = 0.f;
        }
        unsigned short tmp[8];
#pragma unroll
        for (int j = 0; j < 8; ++j) tmp[j] = f2bf(v[j]);
        unsigned short* dp;
        int row = r0 + rl;
        if (!ise2) {
            dp = e1b + (size_t)row * DP + d0;                      // row-major padded
        } else {
            int bb2 = row >> 7, j = row & 127;
            int g8 = d0 >> 3, et = g8 >> 2, gg = g8 & 3;
            dp = e2til + (((size_t)(bb2 * 10 + et) * 4 + gg) * 128 + j) * 8;
        }
        *(short8*)dp = *(short8*)tmp;
    }
}

// ---------- main: per (b,k): S = (e1 Wb[k]) e2^T, gate ----------
// R5 (FROZEN in R6): counted-vmcnt pipeline (T3/T4): wtile 3-deep (60KB),
// e2s 2-deep; iter n issues e2s(n+1) THEN wtile(n+2); barrier is raw
// s_barrier with s_waitcnt vmcnt(5) -- wtile(n+2)'s 5 loads stay in flight
// across the barrier. Issue order e2s-before-wtile pinned (vmcnt counts
// newest-N). LDS 78KB -> 2 blocks/CU; registers at the 2-block unified-RF cap.
template <int SLAB>
__global__ __launch_bounds__(256, 2) void grn_main(
    const unsigned short* __restrict__ e1b, const unsigned short* __restrict__ e2til,
    const unsigned short* __restrict__ wbt,
    const float* __restrict__ p1d, const float* __restrict__ p1g,
    const float* __restrict__ p2d, const float* __restrict__ p2g,
    const float* __restrict__ bg, const float* __restrict__ bb,
    const float* __restrict__ u, float* __restrict__ out, _Float16* __restrict__ slab) {
    const int b = blockIdx.x, k = blockIdx.y;
    const int tid = threadIdx.x;
    const int wid = tid >> 6, lane = tid & 63;
    const int l32 = lane & 31, hi = lane >> 5;
    const int rw0 = wid * 32;                      // wave owns i-rows [rw0, rw0+32)

    __shared__ __align__(16) unsigned short wtile[3][WTILE_E];   // 3 x 20480B
    __shared__ __align__(16) unsigned short e2s[2][E2TILE_E];    // 2 x 8192B
    __shared__ float pbuf[4][128];

    const unsigned short* wsrc = wbt + (size_t)k * WBT_K;
    const unsigned short* esrc = e2til + (size_t)b * (10 * E2TILE_E);

    // prologue stage: e2s(0), wtile(0) first (oldest -> drained by vmcnt(5))
#pragma unroll
    for (int it = 0; it < 2; ++it) {
        int c = wid * 2 + it;
        gload_lds16(esrc + c * 512 + lane * 8, &e2s[0][c * 512]);
    }
#pragma unroll
    for (int it = 0; it < 5; ++it) {
        int c = wid * 5 + it;
        gload_lds16(wsrc + c * 512 + lane * 8, &wtile[0][c * 512]);
    }

    if (tid < 128) {
        int gi = (b * LL + tid) * KDIM + k;
        pbuf[0][tid] = p1d[gi];
        pbuf[1][tid] = p1g[gi];
        pbuf[2][tid] = p2d[gi];
        pbuf[3][tid] = p2g[gi];
    }
    const float u_k = u[k], bg_k = bg[k], b_k = bb[k];

    // e1 B-fragments (phase1): lane holds e1[i=rw0+l32][d=c*16+hi*8+j], c=0..19
    short8 af[20];
    {
        const unsigned short* p = e1b + ((size_t)(b * LL + rw0 + l32)) * DP + hi * 8;
#pragma unroll
        for (int c = 0; c < 20; ++c)
            af[c] = *(const short8*)(p + c * 16);
    }

    float16v S[4];
#pragma unroll
    for (int jt = 0; jt < 4; ++jt)
#pragma unroll
        for (int z = 0; z < 16; ++z) S[jt][z] = 0.f;

    const int swz = (l32 & 7) << 3;                 // phase1 read swizzle (elems)
    const int ebo = hi * 1024 + l32 * 8;            // e2s frag base (elems)

    // prologue stage: wtile(1) LAST (the 5 loads vmcnt(5) leaves in flight)
    __builtin_amdgcn_sched_barrier(0);
#pragma unroll
    for (int it = 0; it < 5; ++it) {
        int c = wid * 5 + it;
        gload_lds16(wsrc + WTILE_E + c * 512 + lane * 8, &wtile[1][c * 512]);
    }
    asm volatile("s_waitcnt vmcnt(5)" ::: "memory");
    __builtin_amdgcn_s_barrier();
    __builtin_amdgcn_sched_barrier(0);

#pragma unroll
    for (int et = 0; et < 10; ++et) {
        const int wr = et % 3;                     // literal (unrolled)
        const int er = et & 1;
        // ks0 B-frags from LDS (current slot)
        short8 b0[4];
#pragma unroll
        for (int jt = 0; jt < 4; ++jt)
            b0[jt] = *(const short8*)&e2s[er][ebo + jt * 256];

        // stage e2s(et+1) FIRST, then wtile(et+2): vmcnt(5) leaves only the
        // wtile(et+2) loads outstanding across the barrier.
        if (et < 9) {
            const unsigned short* es = esrc + (et + 1) * E2TILE_E;
            unsigned short* el = &e2s[er ^ 1][0];
#pragma unroll
            for (int it = 0; it < 2; ++it) {
                int c = wid * 2 + it;
                gload_lds16(es + c * 512 + lane * 8, el + c * 512);
            }
        }
        __builtin_amdgcn_sched_barrier(0);          // pin e2s-before-wtile order
        if (et < 8) {
            const unsigned short* ws = wsrc + (et + 2) * WTILE_E;
            unsigned short* wl = &wtile[(et + 2) % 3][0];
#pragma unroll
            for (int it = 0; it < 5; ++it) {
                int c = wid * 5 + it;
                gload_lds16(ws + c * 512 + lane * 8, wl + c * 512);
            }
        }

        // phase 1 (mfma32): C[m=e'][n=i] = sum_d Wb[e'][d]*e1[i][d]
        const unsigned short* wt = &wtile[wr][l32 * 320];
        float16v t0, t1;
#pragma unroll
        for (int z = 0; z < 16; ++z) { t0[z] = 0.f; t1[z] = 0.f; }
#pragma unroll
        for (int c = 0; c < 20; c += 2) {
            short8 wa0 = *(const short8*)(wt + ((c * 16 + hi * 8) ^ swz));
            short8 wa1 = *(const short8*)(wt + (((c + 1) * 16 + hi * 8) ^ swz));
            t0 = mfma32(wa0, af[c], t0);
            t1 = mfma32(wa1, af[c + 1], t1);
        }
        // ks1 B-frags (LDS; cover = pack/swap + ks0 MFMAs)
        short8 b1[4];
#pragma unroll
        for (int jt = 0; jt < 4; ++jt)
            b1[jt] = *(const short8*)&e2s[er][ebo + 2048 + jt * 256];

        float16v tt = t0 + t1;
        // pack to bf16 pairs; lane (l32,hi) holds T[i=l32][e'=(r&3)+8*(r>>2)+4*hi]
        unsigned int P0 = cvtpk(tt[0], tt[1]);
        unsigned int P1 = cvtpk(tt[2], tt[3]);
        unsigned int P2 = cvtpk(tt[4], tt[5]);
        unsigned int P3 = cvtpk(tt[6], tt[7]);
        unsigned int P4 = cvtpk(tt[8], tt[9]);
        unsigned int P5 = cvtpk(tt[10], tt[11]);
        unsigned int P6 = cvtpk(tt[12], tt[13]);
        unsigned int P7 = cvtpk(tt[14], tt[15]);
        // half-wave exchange: dst'={dst_lo,src_lo}, src'={dst_hi,src_hi}
        int2v r02 = __builtin_amdgcn_permlane32_swap((int)P0, (int)P2, false, false);
        int2v r13 = __builtin_amdgcn_permlane32_swap((int)P1, (int)P3, false, false);
        int2v r46 = __builtin_amdgcn_permlane32_swap((int)P4, (int)P6, false, false);
        int2v r57 = __builtin_amdgcn_permlane32_swap((int)P5, (int)P7, false, false);
        short8 A0 = __builtin_bit_cast(short8, (int4v){r02[0], r13[0], r02[1], r13[1]});
        short8 A1 = __builtin_bit_cast(short8, (int4v){r46[0], r57[0], r46[1], r57[1]});
        // phase 2 (mfma32): S[i][j] += sum_e' T[i][e'] * e2[j][e']
#pragma unroll
        for (int jt = 0; jt < 4; ++jt)
            S[jt] = mfma32(A0, b0[jt], S[jt]);
#pragma unroll
        for (int jt = 0; jt < 4; ++jt)
            S[jt] = mfma32(A1, b1[jt], S[jt]);

        // counted-vmcnt barrier: wtile(et+2) stays in flight (T4).
        if (et < 8) {
            asm volatile("s_waitcnt vmcnt(5)" ::: "memory");
        } else if (et == 8) {
            asm volatile("s_waitcnt vmcnt(0)" ::: "memory");
        }
        if (et < 9) {
            __builtin_amdgcn_s_barrier();
            __builtin_amdgcn_sched_barrier(0);
        }
    }

    // epilogue: gate, mix, scale by u[k]
    // S[jt][r]: i = rw0 + (r&3)+8*(r>>2)+4*hi, j = jt*32 + l32
    float pdj[4], pgj[4];
#pragma unroll
    for (int jt = 0; jt < 4; ++jt) {
        pdj[jt] = pbuf[2][jt * 32 + l32];
        pgj[jt] = pbuf[3][jt * 32 + l32] + bg_k;
    }
    _Float16* sdst = slab + ((size_t)k * NB + b) * 16384;
    float* adst = out + (size_t)b * LL * LL;
#pragma unroll
    for (int r = 0; r < 16; ++r) {
        int i = rw0 + (r & 3) + 8 * (r >> 2) + 4 * hi;
        float pdi_ = pbuf[0][i];
        float pgi_ = pbuf[1][i];
#pragma unroll
        for (int jt = 0; jt < 4; ++jt) {
            float btp = S[jt][r];
            float sd = pdi_ + pdj[jt];
            float sg = pgi_ + pgj[jt];
            float e2x = __expf(2.f * sd);
            float sln = 1.f - 2.f * __builtin_amdgcn_rcpf(e2x + 1.f);   // tanh(sd)
            float g = __builtin_amdgcn_rcpf(1.f + __expf(-sg));          // sigmoid(sg)
            float val = u_k * (g * btp + (1.f - g) * sln + b_k);
            if (SLAB) {
                // permuted coalesced layout: pos = v*256 + tid, v = jt*16 + r
                sdst[(jt * 16 + r) * 256 + tid] = (_Float16)val;
            } else {
                unsafeAtomicAdd(adst + (size_t)i * LL + (jt * 32 + l32), val);
            }
        }
    }
}

// ---------- reduce: out[b][i][j] = sum_k slab[k][b][pos]; decode permutation ----------
__global__ void reduce_k(const _Float16* __restrict__ slab, float* __restrict__ out) {
    int idx = blockIdx.x * 256 + threadIdx.x;     // 0..131071
    int b = idx >> 12;
    int p4 = idx & 4095;
    int pos0 = p4 * 4;
    int v = pos0 >> 8, tid0 = pos0 & 255;
    int jt = v >> 4, r = v & 15;
    int wid = tid0 >> 6, lane = tid0 & 63, hi2 = lane >> 5, l32 = lane & 31;
    int i = wid * 32 + (r & 3) + 8 * (r >> 2) + 4 * hi2;
    int j0 = jt * 32 + l32;

    float a0 = 0.f, a1 = 0.f, a2 = 0.f, a3 = 0.f;
    const _Float16* sp = slab + (size_t)b * 16384 + pos0;
#pragma unroll
    for (int k = 0; k < KDIM; ++k) {
        half4v h = *(const half4v*)(sp + (size_t)k * (NB * 16384));
        a0 += (float)h[0]; a1 += (float)h[1]; a2 += (float)h[2]; a3 += (float)h[3];
    }
    float4 rv; rv.x = a0; rv.y = a1; rv.z = a2; rv.w = a3;
    *(float4*)(out + (size_t)b * 16384 + i * 128 + j0) = rv;
}

extern "C" void kernel_launch(void* const* d_in, const int* in_sizes, int n_in,
                              void* d_out, int out_size, void* d_ws, size_t ws_size,
                              hipStream_t stream) {
    const float* e1 = (const float*)d_in[0];   // (32,128,300)
    const float* e2 = (const float*)d_in[1];   // (32,128,300)
    const float* Wb = (const float*)d_in[2];   // (50,300,300)
    const float* Wd = (const float*)d_in[3];   // (600,50)
    const float* Wg = (const float*)d_in[4];   // (600,50)
    const float* bg = (const float*)d_in[5];   // (50,)
    const float* bb = (const float*)d_in[6];   // (50,)
    const float* u  = (const float*)d_in[7];   // (50,1)
    float* out = (float*)d_out;                // (32,128,128,1)

    unsigned short* e1b   = (unsigned short*)d_ws;               // 1,310,720 elems
    unsigned short* e2til = e1b + 1310720;                       // 1,310,720 elems (tiled)
    unsigned short* wbt   = e2til + 1310720;                     // 5,120,000 elems
    float* pf  = (float*)((char*)d_ws + 15482880);
    float* p1d = pf;
    float* p1g = pf + 204800;
    float* p2d = pf + 409600;
    float* p2g = pf + 614400;                                    // end 18,759,680 B
    _Float16* slab = (_Float16*)((char*)d_ws + SLAB_OFF);        // 50x32x16384 halves

    prep_all<<<1512, 256, 0, stream>>>(e1, e2, Wb, Wd, Wg,
                                       e1b, e2til, wbt,
                                       p1d, p1g, p2d, p2g);

    if (ws_size >= WS_NEED) {
        grn_main<1><<<dim3(NB, KDIM), 256, 0, stream>>>(e1b, e2til, wbt,
                                                        p1d, p1g, p2d, p2g,
                                                        bg, bb, u, out, slab);
        reduce_k<<<512, 256, 0, stream>>>(slab, out);
    } else {
        hipMemsetAsync(d_out, 0, (size_t)out_size * sizeof(float), stream);
        grn_main<0><<<dim3(NB, KDIM), 256, 0, stream>>>(e1b, e2til, wbt,
                                                        p1d, p1g, p2d, p2g,
                                                        bg, bb, u, out, slab);
    }
}